// Round 1
// baseline (254.601 us; speedup 1.0000x reference)
//
#include <hip/hip_runtime.h>
#include <math.h>

// Per-batch-parameterized MLP: 2 -> 36 -> 36 -> 36 -> 1, sin/sin/sin/softplus.
// x: (65536, 2) f32; params: (32, 2809) f32; out: (32, 65536, 1) f32.
//
// Param layout per batch (row-major reshape order):
//   W1 [36][2]  @ 0      b1 [36] @ 72
//   W2 [36][36] @ 108    b2 [36] @ 1404
//   W3 [36][36] @ 1440   b3 [36] @ 2736
//   W4 [1][36]  @ 2772   b4 [1]  @ 2808
//
// Design: one thread per (batch, point). Hidden vectors in registers with
// fully static indexing. Weights are block-uniform -> read via __restrict__
// const global pointer so the compiler can scalarize to s_load (SGPR operand
// feeds v_fmac_f32 directly; keeps the LDS pipe idle).

#define N_PTS 65536
#define NBATCH 32
#define NPAR 2809
#define H 36

__global__ void mlp_fwd_kernel(const float* __restrict__ x,
                               const float* __restrict__ params,
                               float* __restrict__ out)
{
    const int b = blockIdx.y;
    const int n = blockIdx.x * 256 + threadIdx.x;
    const float* __restrict__ p = params + (size_t)b * NPAR;

    const float2 xv = reinterpret_cast<const float2*>(x)[n];

    float h0[H];
    float acc[H];

    // ---- layer 1: 2 -> 36, sin ----
#pragma unroll
    for (int o = 0; o < H; ++o) {
        float a = fmaf(p[2 * o], xv.x, fmaf(p[2 * o + 1], xv.y, p[72 + o]));
        h0[o] = __sinf(a);
    }

    // ---- mid layers: 36 -> 36, sin (x2) ----
    // kept as a real loop (#pragma unroll 1) to keep code size ~I$-friendly;
    // all h0/acc indices remain compile-time constants.
#pragma unroll 1
    for (int L = 0; L < 2; ++L) {
        const int wb = 108 + L * 1332;   // weight base
        const int bb = wb + 1296;        // bias base
#pragma unroll
        for (int o = 0; o < H; ++o) {
            float a = p[bb + o];
#pragma unroll
            for (int i = 0; i < H; ++i)
                a = fmaf(p[wb + o * H + i], h0[i], a);
            acc[o] = a;
        }
#pragma unroll
        for (int o = 0; o < H; ++o)
            h0[o] = __sinf(acc[o]);
    }

    // ---- final layer: 36 -> 1, softplus ----
    float a = p[2808];
#pragma unroll
    for (int i = 0; i < H; ++i)
        a = fmaf(p[2772 + i], h0[i], a);

    // softplus = logaddexp(a, 0) = max(a,0) + log1p(exp(-|a|))  (stable)
    float sp = fmaxf(a, 0.0f) + log1pf(__expf(-fabsf(a)));

    out[(size_t)b * N_PTS + n] = sp;
}

extern "C" void kernel_launch(void* const* d_in, const int* in_sizes, int n_in,
                              void* d_out, int out_size, void* d_ws, size_t ws_size,
                              hipStream_t stream)
{
    const float* x = (const float*)d_in[0];
    const float* params = (const float*)d_in[1];
    float* out = (float*)d_out;

    dim3 grid(N_PTS / 256, NBATCH);
    mlp_fwd_kernel<<<grid, dim3(256), 0, stream>>>(x, params, out);
}

// Round 2
// 248.241 us; speedup vs baseline: 1.0256x; 1.0256x over previous
//
#include <hip/hip_runtime.h>
#include <math.h>

// Per-batch-parameterized MLP: 2 -> 36 -> 36 -> 36 -> 1, sin/sin/sin/softplus.
// x: (65536, 2) f32; params: (32, 2809) f32; out: (32, 65536, 1) f32.
//
// Round-1 change: force weight loads onto the SCALAR pipe. hipcc does not
// scalarize uniform global loads; casting the pointer to the constant
// address space (AS4) makes it emit s_load -> weights arrive in SGPRs and
// feed v_fmac_f32 v, s, v with zero per-weight VALU cost. A pre-kernel
// repacks params into d_ws at a 256B-aligned row stride (2816 floats) so
// wide s_load_dwordx4/x8/x16 are provably legal.

#define N_PTS 65536
#define NBATCH 32
#define NPAR 2809
#define PSTRIDE 2816   // floats; 2816*4 = 11264 B = 44*256 -> 256B-aligned rows
#define H 36

#define CONSTANT_AS __attribute__((address_space(4)))

__device__ __forceinline__ const CONSTANT_AS float* to_const_as(const float* p)
{
    return (const CONSTANT_AS float*)(unsigned long long)p;
}

__global__ void pack_params(const float* __restrict__ src, float* __restrict__ dst)
{
    const int b = blockIdx.y;
    const int t = blockIdx.x * 256 + threadIdx.x;
    if (t < NPAR)
        dst[b * PSTRIDE + t] = src[b * NPAR + t];
}

__global__ void mlp_fwd_kernel(const float* __restrict__ x,
                               const float* __restrict__ params_packed,
                               float* __restrict__ out)
{
    const int b = blockIdx.y;
    const int n = blockIdx.x * 256 + threadIdx.x;
    const CONSTANT_AS float* pc =
        to_const_as(params_packed + (size_t)b * PSTRIDE);

    const float2 xv = reinterpret_cast<const float2*>(x)[n];

    float h0[H];
    float acc[H];

    // ---- layer 1: 2 -> 36, sin ----
#pragma unroll
    for (int o = 0; o < H; ++o) {
        float a = fmaf(pc[2 * o], xv.x, fmaf(pc[2 * o + 1], xv.y, pc[72 + o]));
        h0[o] = __sinf(a);
    }

    // ---- mid layers: 36 -> 36, sin (x2) ----
#pragma unroll 1
    for (int L = 0; L < 2; ++L) {
        const CONSTANT_AS float* w = pc + 108 + L * 1332;   // W rows
        const CONSTANT_AS float* bb = w + 1296;             // biases
#pragma unroll
        for (int o = 0; o < H; ++o) {
            const CONSTANT_AS float* wr = w + o * H;
            // 4 independent accumulator chains -> issue not latency-bound
            float a0 = bb[o], a1 = 0.0f, a2 = 0.0f, a3 = 0.0f;
#pragma unroll
            for (int i = 0; i < H; i += 4) {
                a0 = fmaf(wr[i + 0], h0[i + 0], a0);
                a1 = fmaf(wr[i + 1], h0[i + 1], a1);
                a2 = fmaf(wr[i + 2], h0[i + 2], a2);
                a3 = fmaf(wr[i + 3], h0[i + 3], a3);
            }
            acc[o] = (a0 + a1) + (a2 + a3);
        }
#pragma unroll
        for (int o = 0; o < H; ++o)
            h0[o] = __sinf(acc[o]);
    }

    // ---- final layer: 36 -> 1, softplus ----
    float a0 = pc[2808], a1 = 0.0f, a2 = 0.0f, a3 = 0.0f;
#pragma unroll
    for (int i = 0; i < H; i += 4) {
        a0 = fmaf(pc[2772 + i + 0], h0[i + 0], a0);
        a1 = fmaf(pc[2772 + i + 1], h0[i + 1], a1);
        a2 = fmaf(pc[2772 + i + 2], h0[i + 2], a2);
        a3 = fmaf(pc[2772 + i + 3], h0[i + 3], a3);
    }
    float a = (a0 + a1) + (a2 + a3);

    // softplus = max(a,0) + log1p(exp(-|a|))  (stable)
    float sp = fmaxf(a, 0.0f) + log1pf(__expf(-fabsf(a)));

    out[(size_t)b * N_PTS + n] = sp;
}

extern "C" void kernel_launch(void* const* d_in, const int* in_sizes, int n_in,
                              void* d_out, int out_size, void* d_ws, size_t ws_size,
                              hipStream_t stream)
{
    const float* x = (const float*)d_in[0];
    const float* params = (const float*)d_in[1];
    float* out = (float*)d_out;
    float* packed = (float*)d_ws;   // needs 32*2816*4 = 360448 B of scratch

    dim3 pgrid((NPAR + 255) / 256, NBATCH);
    pack_params<<<pgrid, dim3(256), 0, stream>>>(params, packed);

    dim3 grid(N_PTS / 256, NBATCH);
    mlp_fwd_kernel<<<grid, dim3(256), 0, stream>>>(x, packed, out);
}

// Round 3
// 211.225 us; speedup vs baseline: 1.2054x; 1.1752x over previous
//
#include <hip/hip_runtime.h>
#include <math.h>

// Per-batch-parameterized MLP: 2 -> 36 -> 36 -> 36 -> 1, sin/sin/sin/softplus.
// x: (65536, 2) f32; params: (32, 2809) f32; out: (32, 65536, 1) f32.
//
// Round-2 change: 2 points per thread (same batch -> same weights).
// SMEM returns are out-of-order => every dependent scalar use costs a full
// lgkmcnt(0) drain (~300 cyc). Doubling FMA work per weight-row cluster
// (72 -> 144 cyc/wave) plus 3 resident waves/SIMD covers the stall window.
// h/acc are kept in registers with fully static indexing; sin(acc) is
// written back into h in place (no double-buffer copy).

#define N_PTS 65536
#define NBATCH 32
#define NPAR 2809
#define PSTRIDE 2816   // floats; row stride 11264 B (256B-aligned)
#define H 36

#define CONSTANT_AS __attribute__((address_space(4)))

__device__ __forceinline__ const CONSTANT_AS float* to_const_as(const float* p)
{
    return (const CONSTANT_AS float*)(unsigned long long)p;
}

__global__ void pack_params(const float* __restrict__ src, float* __restrict__ dst)
{
    const int b = blockIdx.y;
    const int t = blockIdx.x * 256 + threadIdx.x;
    if (t < NPAR)
        dst[b * PSTRIDE + t] = src[b * NPAR + t];
}

__global__ __launch_bounds__(256) void mlp_fwd_kernel(
    const float* __restrict__ x,
    const float* __restrict__ params_packed,
    float* __restrict__ out)
{
    const int b = blockIdx.y;
    const int n0 = blockIdx.x * 512 + threadIdx.x;   // point 0
    const int n1 = n0 + 256;                          // point 1
    const CONSTANT_AS float* pc =
        to_const_as(params_packed + (size_t)b * PSTRIDE);

    const float2 xv0 = reinterpret_cast<const float2*>(x)[n0];
    const float2 xv1 = reinterpret_cast<const float2*>(x)[n1];

    float h0[H], h1[H];     // hidden activations, per point
    float a0[H], a1[H];     // pre-activations

    // ---- layer 1: 2 -> 36, sin ----
#pragma unroll
    for (int o = 0; o < H; ++o) {
        const float w0 = pc[2 * o], w1 = pc[2 * o + 1], bo = pc[72 + o];
        h0[o] = __sinf(fmaf(w0, xv0.x, fmaf(w1, xv0.y, bo)));
        h1[o] = __sinf(fmaf(w0, xv1.x, fmaf(w1, xv1.y, bo)));
    }

    // ---- mid layers: 36 -> 36, sin (x2) ----
    // L-loop NOT unrolled: keeps code below the 32 KB I$.
#pragma unroll 1
    for (int L = 0; L < 2; ++L) {
        const CONSTANT_AS float* w = pc + 108 + L * 1332;
        const CONSTANT_AS float* bb = w + 1296;
#pragma unroll
        for (int o = 0; o < H; ++o) {
            const CONSTANT_AS float* wr = w + o * H;
            // 4 independent chains: 2 points x 2 halves
            float s0a = bb[o], s0b = 0.0f, s1a = bb[o], s1b = 0.0f;
#pragma unroll
            for (int i = 0; i < H; i += 2) {
                const float wa = wr[i], wb2 = wr[i + 1];
                s0a = fmaf(wa, h0[i], s0a);
                s0b = fmaf(wb2, h0[i + 1], s0b);
                s1a = fmaf(wa, h1[i], s1a);
                s1b = fmaf(wb2, h1[i + 1], s1b);
            }
            a0[o] = s0a + s0b;
            a1[o] = s1a + s1b;
        }
#pragma unroll
        for (int o = 0; o < H; ++o) {
            h0[o] = __sinf(a0[o]);
            h1[o] = __sinf(a1[o]);
        }
    }

    // ---- final layer: 36 -> 1, softplus ----
    float s0a = pc[2808], s0b = 0.0f, s1a = pc[2808], s1b = 0.0f;
#pragma unroll
    for (int i = 0; i < H; i += 2) {
        const float wa = pc[2772 + i], wb2 = pc[2772 + i + 1];
        s0a = fmaf(wa, h0[i], s0a);
        s0b = fmaf(wb2, h0[i + 1], s0b);
        s1a = fmaf(wa, h1[i], s1a);
        s1b = fmaf(wb2, h1[i + 1], s1b);
    }
    const float v0 = s0a + s0b;
    const float v1 = s1a + s1b;

    // softplus = max(a,0) + log1p(exp(-|a|))  (stable)
    const float r0 = fmaxf(v0, 0.0f) + log1pf(__expf(-fabsf(v0)));
    const float r1 = fmaxf(v1, 0.0f) + log1pf(__expf(-fabsf(v1)));

    out[(size_t)b * N_PTS + n0] = r0;
    out[(size_t)b * N_PTS + n1] = r1;
}

extern "C" void kernel_launch(void* const* d_in, const int* in_sizes, int n_in,
                              void* d_out, int out_size, void* d_ws, size_t ws_size,
                              hipStream_t stream)
{
    const float* x = (const float*)d_in[0];
    const float* params = (const float*)d_in[1];
    float* out = (float*)d_out;
    float* packed = (float*)d_ws;   // 32*2816*4 = 360448 B of scratch

    dim3 pgrid((NPAR + 255) / 256, NBATCH);
    pack_params<<<pgrid, dim3(256), 0, stream>>>(params, packed);

    dim3 grid(N_PTS / 512, NBATCH);
    mlp_fwd_kernel<<<grid, dim3(256), 0, stream>>>(x, packed, out);
}

// Round 4
// 106.951 us; speedup vs baseline: 2.3805x; 1.9750x over previous
//
#include <hip/hip_runtime.h>
#include <hip/hip_bf16.h>
#include <math.h>

// Per-batch MLP 2->36->36->36->1 (sin,sin,sin,softplus), rewritten on MFMA.
// x: (65536,2) f32; params: (32,2809) f32; out: (32,65536) f32.
//
// Formulation per 32-point tile: D = W * h^T using v_mfma_f32_32x32x16_bf16.
//   A = W-ish  (M=outfeat padded to 64 -> 2 feat-tiles, K = 36+bias -> 48 = 3 ksteps)
//   B = h^T    (N = 32 points), bias folded as input slot k==36 with h[36]=1.0
// D layout (HW-verified): col = lane&31 (point), feat = (r&3)+8*(r>>2)+4*(lane>>5).
// Inter-layer: sin on D regs -> pack bf16 pairs -> one shfl_xor(32) exchange
// between the two lane-groups builds the next B fragment. Wave-local: no LDS,
// no barriers. Layer 1 (2->36) on VALU per-lane (lane = point, 64 pts/wave);
// final layer as a 1-real-row MFMA (D row0 lives in reg0 of g0 lanes).

#define NPTS   65536
#define NBATCH 32
#define NPAR   2809
#define PSTRIDE 2816   // packed param row stride (floats); 11264B, 256B-aligned

typedef float        f32x16 __attribute__((ext_vector_type(16)));
typedef short        bf16x8 __attribute__((ext_vector_type(8)));
typedef unsigned int u32;

#define CONSTANT_AS __attribute__((address_space(4)))
__device__ __forceinline__ const CONSTANT_AS float* to_const_as(const float* p)
{
    return (const CONSTANT_AS float*)(unsigned long long)p;
}

union Frag { u32 w[4]; bf16x8 v; };

__device__ __forceinline__ unsigned short f2bf(float f)
{
    __hip_bfloat16 h = __float2bfloat16(f);            // RNE
    union { __hip_bfloat16 b; unsigned short u; } c; c.b = h;
    return c.u;
}
__device__ __forceinline__ u32 pk2(float lo, float hi)  // word = {lo: even k, hi: odd k}
{
    return (u32)f2bf(lo) | ((u32)f2bf(hi) << 16);
}

#define BIAS_WORD 0x00003F80u   // bf16(1.0) in lo half, 0 in hi

__global__ void pack_params(const float* __restrict__ src, float* __restrict__ dst)
{
    const int b = blockIdx.y;
    const int t = blockIdx.x * 256 + threadIdx.x;
    if (t < NPAR)
        dst[b * PSTRIDE + t] = src[b * NPAR + t];
}

// ---- helpers ----------------------------------------------------------------

__device__ __forceinline__ void mfma_pair(const Frag WmL[2][3], const Frag B[3],
                                          f32x16& d1, f32x16& d2)
{
    f32x16 z;
#pragma unroll
    for (int i = 0; i < 16; ++i) z[i] = 0.0f;
    d1 = z; d2 = z;
#pragma unroll
    for (int s = 0; s < 3; ++s) {
        d1 = __builtin_amdgcn_mfma_f32_32x32x16_bf16(WmL[0][s].v, B[s].v, d1, 0, 0, 0);
        d2 = __builtin_amdgcn_mfma_f32_32x32x16_bf16(WmL[1][s].v, B[s].v, d2, 0, 0, 0);
    }
}

// sin(D) -> next-layer B fragment. d1 = feats 0..31, d2 = feats 32..35 (+pad).
__device__ __forceinline__ void buildB_fromD(const f32x16& d1, const f32x16& d2,
                                             bool g1, Frag B[3])
{
    float s1[16];
#pragma unroll
    for (int r = 0; r < 16; ++r) s1[r] = __sinf(d1[r]);
    float s2[4];
#pragma unroll
    for (int r = 0; r < 4; ++r) s2[r] = __sinf(d2[r]);

    // kstep0: k 0..15.  g0 holds feats {0-3,8-11}, g1 holds {4-7,12-15} (r0..7)
    {
        u32 pa0 = pk2(s1[0], s1[1]), pa1 = pk2(s1[2], s1[3]);
        u32 pb0 = pk2(s1[4], s1[5]), pb1 = pk2(s1[6], s1[7]);
        u32 r0 = __shfl_xor(g1 ? pa0 : pb0, 32);
        u32 r1 = __shfl_xor(g1 ? pa1 : pb1, 32);
        B[0].w[0] = g1 ? r0 : pa0;
        B[0].w[1] = g1 ? r1 : pa1;
        B[0].w[2] = g1 ? pb0 : r0;
        B[0].w[3] = g1 ? pb1 : r1;
    }
    // kstep1: k 16..31 from r8..15 (feats 16-31), identical pattern
    {
        u32 pa0 = pk2(s1[8], s1[9]),  pa1 = pk2(s1[10], s1[11]);
        u32 pb0 = pk2(s1[12], s1[13]), pb1 = pk2(s1[14], s1[15]);
        u32 r0 = __shfl_xor(g1 ? pa0 : pb0, 32);
        u32 r1 = __shfl_xor(g1 ? pa1 : pb1, 32);
        B[1].w[0] = g1 ? r0 : pa0;
        B[1].w[1] = g1 ? r1 : pa1;
        B[1].w[2] = g1 ? pb0 : r0;
        B[1].w[3] = g1 ? pb1 : r1;
    }
    // kstep2: k 32..47. g0: feats (32,33),(34,35), bias slot k=36 -> 1.0; g1: pad=0
    {
        u32 q0 = pk2(s2[0], s2[1]), q1 = pk2(s2[2], s2[3]);
        B[2].w[0] = g1 ? 0u : q0;
        B[2].w[1] = g1 ? 0u : q1;
        B[2].w[2] = g1 ? 0u : BIAS_WORD;
        B[2].w[3] = 0u;
    }
}

// Layer-1 packed words (hw[i] = own point's feats 2i,2i+1) -> B frag for a tile.
__device__ __forceinline__ void buildB_fromL1(const u32 hw[18], bool g1, int tileB,
                                              Frag B[3])
{
    if (!tileB) {  // points 0..31 (lanes 0..31 own them)
        u32 r4  = __shfl_xor(hw[4], 32),  r5  = __shfl_xor(hw[5], 32);
        u32 r6  = __shfl_xor(hw[6], 32),  r7  = __shfl_xor(hw[7], 32);
        u32 r12 = __shfl_xor(hw[12], 32), r13 = __shfl_xor(hw[13], 32);
        u32 r14 = __shfl_xor(hw[14], 32), r15 = __shfl_xor(hw[15], 32);
        B[0].w[0] = g1 ? r4 : hw[0];  B[0].w[1] = g1 ? r5 : hw[1];
        B[0].w[2] = g1 ? r6 : hw[2];  B[0].w[3] = g1 ? r7 : hw[3];
        B[1].w[0] = g1 ? r12 : hw[8]; B[1].w[1] = g1 ? r13 : hw[9];
        B[1].w[2] = g1 ? r14 : hw[10]; B[1].w[3] = g1 ? r15 : hw[11];
        B[2].w[0] = g1 ? 0u : hw[16];
        B[2].w[1] = g1 ? 0u : hw[17];
        B[2].w[2] = g1 ? 0u : BIAS_WORD;
        B[2].w[3] = 0u;
    } else {       // points 32..63 (lanes 32..63 own them)
        u32 r0  = __shfl_xor(hw[0], 32),  r1  = __shfl_xor(hw[1], 32);
        u32 r2  = __shfl_xor(hw[2], 32),  r3  = __shfl_xor(hw[3], 32);
        u32 r8  = __shfl_xor(hw[8], 32),  r9  = __shfl_xor(hw[9], 32);
        u32 r10 = __shfl_xor(hw[10], 32), r11 = __shfl_xor(hw[11], 32);
        u32 r16 = __shfl_xor(hw[16], 32), r17 = __shfl_xor(hw[17], 32);
        B[0].w[0] = g1 ? hw[4] : r0;  B[0].w[1] = g1 ? hw[5] : r1;
        B[0].w[2] = g1 ? hw[6] : r2;  B[0].w[3] = g1 ? hw[7] : r3;
        B[1].w[0] = g1 ? hw[12] : r8; B[1].w[1] = g1 ? hw[13] : r9;
        B[1].w[2] = g1 ? hw[14] : r10; B[1].w[3] = g1 ? hw[15] : r11;
        B[2].w[0] = g1 ? 0u : r16;
        B[2].w[1] = g1 ? 0u : r17;
        B[2].w[2] = g1 ? 0u : BIAS_WORD;
        B[2].w[3] = 0u;
    }
}

// ---- main kernel ------------------------------------------------------------

__global__ __launch_bounds__(256) void mlp_mfma_kernel(
    const float* __restrict__ x,
    const float* __restrict__ packed,
    float* __restrict__ out)
{
    const int lane = threadIdx.x & 63;
    const int wave = threadIdx.x >> 6;
    const int b    = blockIdx.y;
    const int c31  = lane & 31;
    const bool g1  = (lane >> 5) != 0;
    const int g    = g1 ? 1 : 0;

    const float* pp = packed + (size_t)b * PSTRIDE;
    const CONSTANT_AS float* pc = to_const_as(pp);

    // ---- one-time: mid-layer W fragments (A-operand), bias folded at k==36 ----
    Frag Wm[2][2][3];   // [layer][feat-tile][kstep]
#pragma unroll
    for (int L = 0; L < 2; ++L) {
        const int wb = 108 + L * 1332;
#pragma unroll
        for (int t = 0; t < 2; ++t) {
            const int r = c31 + 32 * t;   // outfeat row
#pragma unroll
            for (int s = 0; s < 3; ++s) {
                float tv[8];
#pragma unroll
                for (int j = 0; j < 8; ++j) {
                    const int i = 16 * s + 8 * g + j;   // infeat (k)
                    float wv = 0.0f;
                    if (r < 36) {
                        if (i < 36)       wv = pp[wb + 36 * r + i];
                        else if (i == 36) wv = pp[wb + 1296 + r];
                    }
                    tv[j] = wv;
                }
                Frag f;
#pragma unroll
                for (int q = 0; q < 4; ++q) f.w[q] = pk2(tv[2 * q], tv[2 * q + 1]);
                Wm[L][t][s] = f;
            }
        }
    }
    // ---- one-time: final-layer W4 fragment (row 0 only; bias at k==36) ----
    Frag W4f[3];
#pragma unroll
    for (int s = 0; s < 3; ++s) {
        float tv[8];
#pragma unroll
        for (int j = 0; j < 8; ++j) {
            const int i = 16 * s + 8 * g + j;
            float wv = 0.0f;
            if (c31 == 0) {
                if (i < 36)       wv = pp[2772 + i];
                else if (i == 36) wv = pp[2808];
            }
            tv[j] = wv;
        }
        Frag f;
#pragma unroll
        for (int q = 0; q < 4; ++q) f.w[q] = pk2(tv[2 * q], tv[2 * q + 1]);
        W4f[s] = f;
    }

    // ---- 4 iterations x 64 points per wave ----
#pragma unroll 1
    for (int it = 0; it < 4; ++it) {
        const int nb = blockIdx.x * 1024 + wave * 256 + it * 64;
        const int n  = nb + lane;
        const float2 xv = reinterpret_cast<const float2*>(x)[n];

        // layer 1 on VALU: lane = point; pack 36 feats into 18 bf16x2 words
        u32 hw[18];
#pragma unroll
        for (int o2 = 0; o2 < 18; ++o2) {
            const float a0 = fmaf(pc[4 * o2 + 0], xv.x,
                             fmaf(pc[4 * o2 + 1], xv.y, pc[72 + 2 * o2 + 0]));
            const float a1 = fmaf(pc[4 * o2 + 2], xv.x,
                             fmaf(pc[4 * o2 + 3], xv.y, pc[72 + 2 * o2 + 1]));
            hw[o2] = pk2(__sinf(a0), __sinf(a1));
        }

        Frag B[3];
        f32x16 dA1, dA2, dB1, dB2;

        // layer 2
        buildB_fromL1(hw, g1, 0, B);
        mfma_pair(Wm[0], B, dA1, dA2);
        buildB_fromL1(hw, g1, 1, B);
        mfma_pair(Wm[0], B, dB1, dB2);

        // layer 3
        buildB_fromD(dA1, dA2, g1, B);
        mfma_pair(Wm[1], B, dA1, dA2);
        buildB_fromD(dB1, dB2, g1, B);
        mfma_pair(Wm[1], B, dB1, dB2);

        // final layer: 1-real-row MFMA; D row0 = reg0 at g0 lanes
        f32x16 fA, fB;
        {
            buildB_fromD(dA1, dA2, g1, B);
            f32x16 z;
#pragma unroll
            for (int i = 0; i < 16; ++i) z[i] = 0.0f;
            fA = z;
#pragma unroll
            for (int s = 0; s < 3; ++s)
                fA = __builtin_amdgcn_mfma_f32_32x32x16_bf16(W4f[s].v, B[s].v, fA, 0, 0, 0);

            buildB_fromD(dB1, dB2, g1, B);
            fB = z;
#pragma unroll
            for (int s = 0; s < 3; ++s)
                fB = __builtin_amdgcn_mfma_f32_32x32x16_bf16(W4f[s].v, B[s].v, fB, 0, 0, 0);
        }

        // softplus + store (stable form)
        const float vA = fA[0];
        const float vB = fB[0];
        const float spA = fmaxf(vA, 0.0f) + log1pf(__expf(-fabsf(vA)));
        const float spB = fmaxf(vB, 0.0f) + log1pf(__expf(-fabsf(vB)));
        const float spBx = __shfl_xor(spB, 32);   // move tileB results to lanes 32..63
        const float outv = (lane < 32) ? spA : spBx;

        out[(size_t)b * NPTS + n] = outv;
    }
}

extern "C" void kernel_launch(void* const* d_in, const int* in_sizes, int n_in,
                              void* d_out, int out_size, void* d_ws, size_t ws_size,
                              hipStream_t stream)
{
    const float* x = (const float*)d_in[0];
    const float* params = (const float*)d_in[1];
    float* out = (float*)d_out;
    float* packed = (float*)d_ws;   // 32*2816*4 = 360448 B scratch

    dim3 pgrid((NPAR + 255) / 256, NBATCH);
    pack_params<<<pgrid, dim3(256), 0, stream>>>(params, packed);

    dim3 grid(NPTS / 1024, NBATCH);   // 64 x 32 blocks, 4 waves each
    mlp_mfma_kernel<<<grid, dim3(256), 0, stream>>>(x, packed, out);
}

// Round 7
// 85.897 us; speedup vs baseline: 2.9640x; 1.2451x over previous
//
#include <hip/hip_runtime.h>
#include <math.h>

// Per-batch MLP 2->36->36->36->1 (sin,sin,sin,softplus) on MFMA, round 7.
// x: (65536,2) f32; params: (32,2809) f32; out: (32,65536) f32.
//
// Formulation per 32-point tile: D = W * h^T, v_mfma_f32_32x32x16_bf16.
//   A = W (M=outfeat pad 64 -> 2 tiles, K=36+bias -> 48 = 3 ksteps)
//   B = h^T (N=32 points), bias folded at k==36 with h[36]=1.0.
// D layout (HW-verified): col=lane&31 (point), feat=(r&3)+8*(r>>2)+4*(lane>>5).
//
// Round-7 = CORRECTNESS BISECT. Round 6 failed at absmax 0.098; the
// permlane32_swap data movement is element-identical to round 4's proven
// shfl/cndmask path (and any mis-orientation would destroy the final output
// merge -> O(1) error, not 0.098), so the suspects are the two NUMERIC
// substitutions. This round reverts both to round-4-proven forms:
//   - bf16 packing: software round-to-nearest-even (bit-exact vs round 4's
//     __float2bfloat16) instead of v_cvt_pk_bf16_f32 inline asm.
//   - sin: __sinf on UNSCALED (radians) weights -- the 1/(2pi) fold into
//     W/b and raw __builtin_amdgcn_sinf are removed.
// Kept from round 6 (structural, exonerated): permlane32_swap exchanges,
// per-block LDS weight-fragment build (15x64 uint4 = 15,360 B), 16 KB d_ws.

#define NPTS     65536
#define NBATCH   32
#define NPAR     2809
#define L1N      108    // W1+b1 floats
#define L1STRIDE 128    // L1 row stride in ws (512 B)

typedef float        f32x16 __attribute__((ext_vector_type(16)));
typedef short        bf16x8 __attribute__((ext_vector_type(8)));
typedef unsigned int u32;
typedef unsigned int u32x2 __attribute__((ext_vector_type(2)));

#define CONSTANT_AS __attribute__((address_space(4)))
static __device__ __forceinline__ const CONSTANT_AS float* to_const_as(const float* p)
{ return (const CONSTANT_AS float*)(unsigned long long)p; }

// software bf16 round-to-nearest-even (inputs are finite: sins & small weights)
static __device__ __forceinline__ u32 bfrne(float f)
{
    const u32 u = __float_as_uint(f);
    return (u + 0x7fffu + ((u >> 16) & 1u)) >> 16;
}
static __device__ __forceinline__ u32 pk2(float lo, float hi)   // {lo: even k, hi: odd k}
{ return bfrne(lo) | (bfrne(hi) << 16); }

// swap a's hi-32-lanes with b's lo-32-lanes; returns {new_a, new_b}
static __device__ __forceinline__ u32x2 plsw(u32 a, u32 b)
{ return __builtin_amdgcn_permlane32_swap(a, b, false, false); }

static __device__ __forceinline__ bf16x8 mkfrag(u32 w0, u32 w1, u32 w2, u32 w3)
{
    union { u32 u[4]; bf16x8 v; } c;
    c.u[0] = w0; c.u[1] = w1; c.u[2] = w2; c.u[3] = w3;
    return c.v;
}
static __device__ __forceinline__ bf16x8 u4frag(uint4 u)
{ union { uint4 a; bf16x8 v; } c; c.a = u; return c.v; }

static __device__ __forceinline__ f32x16 mfma(bf16x8 a, bf16x8 b, f32x16 c)
{ return __builtin_amdgcn_mfma_f32_32x32x16_bf16(a, b, c, 0, 0, 0); }

// round-4 proven stable softplus
static __device__ __forceinline__ float softplus(float a)
{ return fmaxf(a, 0.0f) + log1pf(__expf(-fabsf(a))); }

// ---- setup kernel: layer-1 params at s_load-friendly stride (16 KB d_ws) ----

__global__ void pack_l1(const float* __restrict__ src, float* __restrict__ dst)
{
    const int b = blockIdx.x;
    const int t = threadIdx.x;
    if (t < L1N)
        dst[b * L1STRIDE + t] = src[(size_t)b * NPAR + t];   // NO scaling (radians)
}

// ---- per-slot weight-fragment gather (round-4 layout, no scaling) -----------
// Frag ids: mid layers f = 6L + 3t + s; final layer f = 12+s.

static __device__ __forceinline__ uint4 build_frag_slot(
    const float* __restrict__ pp, int f, int l)
{
    const int c31 = l & 31;
    const int g   = l >> 5;
    float tv[8];
#pragma unroll
    for (int j = 0; j < 8; ++j) tv[j] = 0.0f;

    if (f < 12) {
        const int L = f / 6, t = (f % 6) / 3, s = f % 3;
        const int wb = 108 + L * 1332;
        const int r  = c31 + 32 * t;                 // outfeat row
        if (r < 36) {
#pragma unroll
            for (int j = 0; j < 8; ++j) {
                const int i = 16 * s + 8 * g + j;    // infeat (k)
                if (i < 36)       tv[j] = pp[wb + 36 * r + i];
                else if (i == 36) tv[j] = pp[wb + 1296 + r];   // bias slot
            }
        }
    } else {
        const int s = f - 12;
        if (c31 == 0) {                              // only row 0 is real
#pragma unroll
            for (int j = 0; j < 8; ++j) {
                const int i = 16 * s + 8 * g + j;
                if (i < 36)       tv[j] = pp[2772 + i];      // W4
                else if (i == 36) tv[j] = pp[2808];          // b4
            }
        }
    }
    uint4 o;
    o.x = pk2(tv[0], tv[1]); o.y = pk2(tv[2], tv[3]);
    o.z = pk2(tv[4], tv[5]); o.w = pk2(tv[6], tv[7]);
    return o;
}

// ---- B-fragment builder: sin(D) -> next-layer B frag (12 words) -------------

static __device__ __forceinline__ void buildB(const f32x16& d1, const f32x16& d2,
                                              u32 biasw, u32 F[12])
{
    float s1[16];
#pragma unroll
    for (int r = 0; r < 16; ++r) s1[r] = __sinf(d1[r]);
    u32 c[8];
#pragma unroll
    for (int q = 0; q < 8; ++q) c[q] = pk2(s1[2 * q], s1[2 * q + 1]);
    const u32 q0 = pk2(__sinf(d2[0]), __sinf(d2[1]));
    const u32 q1 = pk2(__sinf(d2[2]), __sinf(d2[3]));

    u32x2 r;
    r = plsw(c[0], c[2]); F[0] = r.x; F[2] = r.y;   // kstep0
    r = plsw(c[1], c[3]); F[1] = r.x; F[3] = r.y;
    r = plsw(c[4], c[6]); F[4] = r.x; F[6] = r.y;   // kstep1
    r = plsw(c[5], c[7]); F[5] = r.x; F[7] = r.y;
    F[8] = q0; F[9] = q1; F[10] = biasw; F[11] = 0; // kstep2 (g1 A-side is 0)
}

// ---- main kernel ------------------------------------------------------------

__global__ __launch_bounds__(256) void mlp_mfma_kernel(
    const float* __restrict__ x,
    const float* __restrict__ params,     // original (32,2809)
    const float* __restrict__ l1p,        // L1 params, stride 128
    float* __restrict__ out)
{
    __shared__ uint4 lds_fw[15 * 64];

    const int lane = threadIdx.x & 63;
    const int wave = threadIdx.x >> 6;
    const int b    = blockIdx.y;

    // ---- phase 0: cooperative frag build into LDS (once per block) ----
    {
        const float* pp = params + (size_t)b * NPAR;
#pragma unroll
        for (int k = 0; k < 4; ++k) {
            const int sid = threadIdx.x + 256 * k;   // 0..1023; 960 real slots
            if (sid < 960)
                lds_fw[sid] = build_frag_slot(pp, sid >> 6, sid & 63);
        }
    }
    __syncthreads();

    uint4 W[15];
#pragma unroll
    for (int f = 0; f < 15; ++f)
        W[f] = lds_fw[f * 64 + lane];

    const CONSTANT_AS float* pc = to_const_as(l1p + (size_t)b * L1STRIDE);
    const u32 biasw = pk2(1.0f, 0.0f);

    f32x16 z;
#pragma unroll
    for (int i = 0; i < 16; ++i) z[i] = 0.0f;

#pragma unroll 1
    for (int it = 0; it < 4; ++it) {
        const int n = blockIdx.x * 1024 + wave * 256 + it * 64 + lane;
        const float2 xv = reinterpret_cast<const float2*>(x)[n];

        // ---- layer 1 on VALU (lane = point): 36 feats -> 18 bf16x2 words
        u32 hw[18];
#pragma unroll
        for (int o2 = 0; o2 < 18; ++o2) {
            const float a0 = fmaf(pc[4 * o2 + 0], xv.x,
                             fmaf(pc[4 * o2 + 1], xv.y, pc[72 + 2 * o2 + 0]));
            const float a1 = fmaf(pc[4 * o2 + 2], xv.x,
                             fmaf(pc[4 * o2 + 3], xv.y, pc[72 + 2 * o2 + 1]));
            hw[o2] = pk2(__sinf(a0), __sinf(a1));
        }

        // ---- both point-tile B frags from layer-1 output (10 swaps)
        u32 FA[12], FB[12];
#pragma unroll
        for (int q = 0; q < 4; ++q) {
            u32x2 r0 = plsw(hw[q],     hw[4 + q]);  FA[q]     = r0.x; FB[q]     = r0.y;
            u32x2 r1 = plsw(hw[8 + q], hw[12 + q]); FA[4 + q] = r1.x; FB[4 + q] = r1.y;
        }
        FA[8] = hw[16]; FA[9] = hw[17];
        { u32x2 r = plsw(hw[16], hw[16]); FB[8] = r.y; }
        { u32x2 r = plsw(hw[17], hw[17]); FB[9] = r.y; }
        FA[10] = biasw; FA[11] = 0; FB[10] = biasw; FB[11] = 0;

        // ---- layer 2 (frags 0..5)
        f32x16 dA1 = z, dA2 = z, dB1 = z, dB2 = z;
#pragma unroll
        for (int s = 0; s < 3; ++s) {
            const bf16x8 ba = mkfrag(FA[4*s], FA[4*s+1], FA[4*s+2], FA[4*s+3]);
            const bf16x8 bb = mkfrag(FB[4*s], FB[4*s+1], FB[4*s+2], FB[4*s+3]);
            dA1 = mfma(u4frag(W[s]),     ba, dA1);
            dA2 = mfma(u4frag(W[3 + s]), ba, dA2);
            dB1 = mfma(u4frag(W[s]),     bb, dB1);
            dB2 = mfma(u4frag(W[3 + s]), bb, dB2);
        }

        // ---- layer 3 (frags 6..11)
        buildB(dA1, dA2, biasw, FA);
        buildB(dB1, dB2, biasw, FB);
        dA1 = z; dA2 = z; dB1 = z; dB2 = z;
#pragma unroll
        for (int s = 0; s < 3; ++s) {
            const bf16x8 ba = mkfrag(FA[4*s], FA[4*s+1], FA[4*s+2], FA[4*s+3]);
            const bf16x8 bb = mkfrag(FB[4*s], FB[4*s+1], FB[4*s+2], FB[4*s+3]);
            dA1 = mfma(u4frag(W[6 + s]), ba, dA1);
            dA2 = mfma(u4frag(W[9 + s]), ba, dA2);
            dB1 = mfma(u4frag(W[6 + s]), bb, dB1);
            dB2 = mfma(u4frag(W[9 + s]), bb, dB2);
        }

        // ---- final layer (frags 12..14): D row0 = reg0 at g0 lanes
        buildB(dA1, dA2, biasw, FA);
        buildB(dB1, dB2, biasw, FB);
        f32x16 fA = z, fB = z;
#pragma unroll
        for (int s = 0; s < 3; ++s) {
            fA = mfma(u4frag(W[12 + s]),
                      mkfrag(FA[4*s], FA[4*s+1], FA[4*s+2], FA[4*s+3]), fA);
            fB = mfma(u4frag(W[12 + s]),
                      mkfrag(FB[4*s], FB[4*s+1], FB[4*s+2], FB[4*s+3]), fB);
        }

        // ---- softplus + merged store (tile A -> lanes 0..31, B -> 32..63)
        const float spA = softplus(fA[0]);
        const float spB = softplus(fB[0]);
        const u32x2 r = plsw(__float_as_uint(spA), __float_as_uint(spB));
        out[(size_t)b * NPTS + n] = __uint_as_float(r.x);
    }
}

extern "C" void kernel_launch(void* const* d_in, const int* in_sizes, int n_in,
                              void* d_out, int out_size, void* d_ws, size_t ws_size,
                              hipStream_t stream)
{
    const float* x = (const float*)d_in[0];
    const float* params = (const float*)d_in[1];
    float* out = (float*)d_out;
    float* l1p = (float*)d_ws;   // 32*128*4 = 16,384 B — inside proven ws use

    pack_l1<<<dim3(NBATCH), dim3(128), 0, stream>>>(params, l1p);

    mlp_mfma_kernel<<<dim3(NPTS / 1024, NBATCH), dim3(256), 0, stream>>>(
        x, params, l1p, out);
}

// Round 8
// 71.873 us; speedup vs baseline: 3.5424x; 1.1951x over previous
//
#include <hip/hip_runtime.h>
#include <math.h>

// Per-batch MLP 2->36->36->36->1 (sin,sin,sin,softplus) on MFMA, round 8.
// x: (65536,2) f32; params: (32,2809) f32; out: (32,65536) f32.
//
// Formulation per 32-point tile: D = W * h^T, v_mfma_f32_32x32x16_bf16.
//   A = W (M=outfeat pad 64 -> 2 tiles, K=36+bias -> 48 = 3 ksteps)
//   B = h^T (N=32 points), bias folded at k==36 with h[36]=1.0.
// D layout (HW-verified): col=lane&31 (point), feat=(r&3)+8*(r>>2)+4*(lane>>5).
//
// Round-8: VALU diet on the PROVEN round-7 numeric path (no semantic change):
//  - softplus: log1pf libcall (~40 branchy insts) -> __logf(1+t). Argument
//    1+t in (1,2] so v_log is exact to ~1e-7 abs, no cancellation. (Round 5's
//    bug was an extra *0.693 on top of __logf, which is already natural log.)
//  - pk2: BIT-EXACT 5-inst form: rnd16 = u + 0x7fff + ((u>>16)&1) per value,
//    then one v_perm_b32 grabs both high halves. Same bits as round 7.
// Frozen: software-RNE bf16 rounding, __sinf radians, permlane32_swap
// exchanges, per-block LDS frag build (15x64 uint4), 16 KB d_ws.

#define NPTS     65536
#define NBATCH   32
#define NPAR     2809
#define L1N      108    // W1+b1 floats
#define L1STRIDE 128    // L1 row stride in ws (512 B)

typedef float        f32x16 __attribute__((ext_vector_type(16)));
typedef short        bf16x8 __attribute__((ext_vector_type(8)));
typedef unsigned int u32;
typedef unsigned int u32x2 __attribute__((ext_vector_type(2)));

#define CONSTANT_AS __attribute__((address_space(4)))
static __device__ __forceinline__ const CONSTANT_AS float* to_const_as(const float* p)
{ return (const CONSTANT_AS float*)(unsigned long long)p; }

// round-to-nearest-even: high 16 bits of (u + 0x7fff + lsb-of-high-half)
static __device__ __forceinline__ u32 rnd16(float f)
{
    const u32 u = __float_as_uint(f);
    return u + 0x7fffu + ((u >> 16) & 1u);
}
// pack {bf16(lo), bf16(hi)} -- bit-exact vs round 7's bfrne/shift form.
// v_perm_b32: D.byte_i selects from concat(S0:S1); sel 0x07060302 takes
// S1[31:16] -> D[15:0] and S0[31:16] -> D[31:16].
static __device__ __forceinline__ u32 pk2(float lo, float hi)
{ return __builtin_amdgcn_perm(rnd16(hi), rnd16(lo), 0x07060302u); }

// swap a's hi-32-lanes with b's lo-32-lanes; returns {new_a, new_b}
static __device__ __forceinline__ u32x2 plsw(u32 a, u32 b)
{ return __builtin_amdgcn_permlane32_swap(a, b, false, false); }

static __device__ __forceinline__ bf16x8 mkfrag(u32 w0, u32 w1, u32 w2, u32 w3)
{
    union { u32 u[4]; bf16x8 v; } c;
    c.u[0] = w0; c.u[1] = w1; c.u[2] = w2; c.u[3] = w3;
    return c.v;
}
static __device__ __forceinline__ bf16x8 u4frag(uint4 u)
{ union { uint4 a; bf16x8 v; } c; c.a = u; return c.v; }

static __device__ __forceinline__ f32x16 mfma(bf16x8 a, bf16x8 b, f32x16 c)
{ return __builtin_amdgcn_mfma_f32_32x32x16_bf16(a, b, c, 0, 0, 0); }

// stable softplus; 1+t in (1,2] -> __logf exact to ~1e-7 abs (no libcall)
static __device__ __forceinline__ float softplus(float a)
{ return fmaxf(a, 0.0f) + __logf(1.0f + __expf(-fabsf(a))); }

// ---- setup kernel: layer-1 params at s_load-friendly stride (16 KB d_ws) ----

__global__ void pack_l1(const float* __restrict__ src, float* __restrict__ dst)
{
    const int b = blockIdx.x;
    const int t = threadIdx.x;
    if (t < L1N)
        dst[b * L1STRIDE + t] = src[(size_t)b * NPAR + t];
}

// ---- per-slot weight-fragment gather --------------------------------------
// Frag ids: mid layers f = 6L + 3t + s; final layer f = 12+s.

static __device__ __forceinline__ uint4 build_frag_slot(
    const float* __restrict__ pp, int f, int l)
{
    const int c31 = l & 31;
    const int g   = l >> 5;
    float tv[8];
#pragma unroll
    for (int j = 0; j < 8; ++j) tv[j] = 0.0f;

    if (f < 12) {
        const int L = f / 6, t = (f % 6) / 3, s = f % 3;
        const int wb = 108 + L * 1332;
        const int r  = c31 + 32 * t;                 // outfeat row
        if (r < 36) {
#pragma unroll
            for (int j = 0; j < 8; ++j) {
                const int i = 16 * s + 8 * g + j;    // infeat (k)
                if (i < 36)       tv[j] = pp[wb + 36 * r + i];
                else if (i == 36) tv[j] = pp[wb + 1296 + r];   // bias slot
            }
        }
    } else {
        const int s = f - 12;
        if (c31 == 0) {                              // only row 0 is real
#pragma unroll
            for (int j = 0; j < 8; ++j) {
                const int i = 16 * s + 8 * g + j;
                if (i < 36)       tv[j] = pp[2772 + i];      // W4
                else if (i == 36) tv[j] = pp[2808];          // b4
            }
        }
    }
    uint4 o;
    o.x = pk2(tv[0], tv[1]); o.y = pk2(tv[2], tv[3]);
    o.z = pk2(tv[4], tv[5]); o.w = pk2(tv[6], tv[7]);
    return o;
}

// ---- B-fragment builder: sin(D) -> next-layer B frag (12 words) -------------

static __device__ __forceinline__ void buildB(const f32x16& d1, const f32x16& d2,
                                              u32 biasw, u32 F[12])
{
    float s1[16];
#pragma unroll
    for (int r = 0; r < 16; ++r) s1[r] = __sinf(d1[r]);
    u32 c[8];
#pragma unroll
    for (int q = 0; q < 8; ++q) c[q] = pk2(s1[2 * q], s1[2 * q + 1]);
    const u32 q0 = pk2(__sinf(d2[0]), __sinf(d2[1]));
    const u32 q1 = pk2(__sinf(d2[2]), __sinf(d2[3]));

    u32x2 r;
    r = plsw(c[0], c[2]); F[0] = r.x; F[2] = r.y;   // kstep0
    r = plsw(c[1], c[3]); F[1] = r.x; F[3] = r.y;
    r = plsw(c[4], c[6]); F[4] = r.x; F[6] = r.y;   // kstep1
    r = plsw(c[5], c[7]); F[5] = r.x; F[7] = r.y;
    F[8] = q0; F[9] = q1; F[10] = biasw; F[11] = 0; // kstep2 (g1 A-side is 0)
}

// ---- main kernel ------------------------------------------------------------

__global__ __launch_bounds__(256) void mlp_mfma_kernel(
    const float* __restrict__ x,
    const float* __restrict__ params,     // original (32,2809)
    const float* __restrict__ l1p,        // L1 params, stride 128
    float* __restrict__ out)
{
    __shared__ uint4 lds_fw[15 * 64];

    const int lane = threadIdx.x & 63;
    const int wave = threadIdx.x >> 6;
    const int b    = blockIdx.y;

    // ---- phase 0: cooperative frag build into LDS (once per block) ----
    {
        const float* pp = params + (size_t)b * NPAR;
#pragma unroll
        for (int k = 0; k < 4; ++k) {
            const int sid = threadIdx.x + 256 * k;   // 0..1023; 960 real slots
            if (sid < 960)
                lds_fw[sid] = build_frag_slot(pp, sid >> 6, sid & 63);
        }
    }
    __syncthreads();

    uint4 W[15];
#pragma unroll
    for (int f = 0; f < 15; ++f)
        W[f] = lds_fw[f * 64 + lane];

    const CONSTANT_AS float* pc = to_const_as(l1p + (size_t)b * L1STRIDE);
    const u32 biasw = pk2(1.0f, 0.0f);

    f32x16 z;
#pragma unroll
    for (int i = 0; i < 16; ++i) z[i] = 0.0f;

#pragma unroll 1
    for (int it = 0; it < 4; ++it) {
        const int n = blockIdx.x * 1024 + wave * 256 + it * 64 + lane;
        const float2 xv = reinterpret_cast<const float2*>(x)[n];

        // ---- layer 1 on VALU (lane = point): 36 feats -> 18 bf16x2 words
        u32 hw[18];
#pragma unroll
        for (int o2 = 0; o2 < 18; ++o2) {
            const float a0 = fmaf(pc[4 * o2 + 0], xv.x,
                             fmaf(pc[4 * o2 + 1], xv.y, pc[72 + 2 * o2 + 0]));
            const float a1 = fmaf(pc[4 * o2 + 2], xv.x,
                             fmaf(pc[4 * o2 + 3], xv.y, pc[72 + 2 * o2 + 1]));
            hw[o2] = pk2(__sinf(a0), __sinf(a1));
        }

        // ---- both point-tile B frags from layer-1 output (10 swaps)
        u32 FA[12], FB[12];
#pragma unroll
        for (int q = 0; q < 4; ++q) {
            u32x2 r0 = plsw(hw[q],     hw[4 + q]);  FA[q]     = r0.x; FB[q]     = r0.y;
            u32x2 r1 = plsw(hw[8 + q], hw[12 + q]); FA[4 + q] = r1.x; FB[4 + q] = r1.y;
        }
        FA[8] = hw[16]; FA[9] = hw[17];
        { u32x2 r = plsw(hw[16], hw[16]); FB[8] = r.y; }
        { u32x2 r = plsw(hw[17], hw[17]); FB[9] = r.y; }
        FA[10] = biasw; FA[11] = 0; FB[10] = biasw; FB[11] = 0;

        // ---- layer 2 (frags 0..5)
        f32x16 dA1 = z, dA2 = z, dB1 = z, dB2 = z;
#pragma unroll
        for (int s = 0; s < 3; ++s) {
            const bf16x8 ba = mkfrag(FA[4*s], FA[4*s+1], FA[4*s+2], FA[4*s+3]);
            const bf16x8 bb = mkfrag(FB[4*s], FB[4*s+1], FB[4*s+2], FB[4*s+3]);
            dA1 = mfma(u4frag(W[s]),     ba, dA1);
            dA2 = mfma(u4frag(W[3 + s]), ba, dA2);
            dB1 = mfma(u4frag(W[s]),     bb, dB1);
            dB2 = mfma(u4frag(W[3 + s]), bb, dB2);
        }

        // ---- layer 3 (frags 6..11)
        buildB(dA1, dA2, biasw, FA);
        buildB(dB1, dB2, biasw, FB);
        dA1 = z; dA2 = z; dB1 = z; dB2 = z;
#pragma unroll
        for (int s = 0; s < 3; ++s) {
            const bf16x8 ba = mkfrag(FA[4*s], FA[4*s+1], FA[4*s+2], FA[4*s+3]);
            const bf16x8 bb = mkfrag(FB[4*s], FB[4*s+1], FB[4*s+2], FB[4*s+3]);
            dA1 = mfma(u4frag(W[6 + s]), ba, dA1);
            dA2 = mfma(u4frag(W[9 + s]), ba, dA2);
            dB1 = mfma(u4frag(W[6 + s]), bb, dB1);
            dB2 = mfma(u4frag(W[9 + s]), bb, dB2);
        }

        // ---- final layer (frags 12..14): D row0 = reg0 at g0 lanes
        buildB(dA1, dA2, biasw, FA);
        buildB(dB1, dB2, biasw, FB);
        f32x16 fA = z, fB = z;
#pragma unroll
        for (int s = 0; s < 3; ++s) {
            fA = mfma(u4frag(W[12 + s]),
                      mkfrag(FA[4*s], FA[4*s+1], FA[4*s+2], FA[4*s+3]), fA);
            fB = mfma(u4frag(W[12 + s]),
                      mkfrag(FB[4*s], FB[4*s+1], FB[4*s+2], FB[4*s+3]), fB);
        }

        // ---- softplus + merged store (tile A -> lanes 0..31, B -> 32..63)
        const float spA = softplus(fA[0]);
        const float spB = softplus(fB[0]);
        const u32x2 r = plsw(__float_as_uint(spA), __float_as_uint(spB));
        out[(size_t)b * NPTS + n] = __uint_as_float(r.x);
    }
}

extern "C" void kernel_launch(void* const* d_in, const int* in_sizes, int n_in,
                              void* d_out, int out_size, void* d_ws, size_t ws_size,
                              hipStream_t stream)
{
    const float* x = (const float*)d_in[0];
    const float* params = (const float*)d_in[1];
    float* out = (float*)d_out;
    float* l1p = (float*)d_ws;   // 32*128*4 = 16,384 B — inside proven ws use

    pack_l1<<<dim3(NBATCH), dim3(128), 0, stream>>>(params, l1p);

    mlp_mfma_kernel<<<dim3(NPTS / 1024, NBATCH), dim3(256), 0, stream>>>(
        x, params, l1p, out);
}

// Round 9
// 65.112 us; speedup vs baseline: 3.9102x; 1.1038x over previous
//
#include <hip/hip_runtime.h>
#include <math.h>

// Per-batch MLP 2->36->36->36->1 (sin,sin,sin,softplus) on MFMA, round 9.
// x: (65536,2) f32; params: (32,2809) f32; out: (32,65536) f32.
//
// Formulation per 32-point tile: D = W * h^T, v_mfma_f32_32x32x16_bf16.
//   A = W (M=outfeat pad 64 -> 2 tiles, K=36+bias -> 48 = 3 ksteps)
//   B = h^T (N=32 points), bias at k==36 with h[36]=1.0.
// D layout (HW-verified): col=lane&31 (point), feat=(r&3)+8*(r>>2)+4*(lane>>5).
//
// Round-9: REGISTER-FOOTPRINT restructure (numerics frozen). Round 8 had 10
// live f32x16 accumulators (160 regs) -> compiler spilled them to AGPRs
// (VGPR=124 shown + ~160 AGPR hidden = ~330 regs/wave = 1.56 waves/SIMD
// occupancy, ~19.5%) and emitted ~1300 v_accvgpr_read/write per iter (the
// measured-vs-static VALU gap). Changes:
//  - Tiles A and B processed SERIALLY per iteration: live accs 160 -> 32.
//  - Final layer on VALU: after layer 3 each lane holds its own point's
//    feats (mapping (r&3)+8*(r>>2)+4g, same one buildB is proven against);
//    20 f32 fma + plsw pair-reduce + b4 + softplus. Removes 2 buildB
//    packings, 6 MFMAs, 32 acc regs; f32 final dot = strictly more accurate.
// Frozen: software-RNE pk2 (bit-exact), __sinf radians, permlane32_swap
// exchanges, per-block LDS frag build (now 12 frags = 12,288 B), 16 KB d_ws.

#define NPTS     65536
#define NBATCH   32
#define NPAR     2809
#define L1N      108
#define L1STRIDE 128    // L1 row stride in ws (512 B)

typedef float        f32x16 __attribute__((ext_vector_type(16)));
typedef short        bf16x8 __attribute__((ext_vector_type(8)));
typedef unsigned int u32;
typedef unsigned int u32x2 __attribute__((ext_vector_type(2)));

#define CONSTANT_AS __attribute__((address_space(4)))
static __device__ __forceinline__ const CONSTANT_AS float* to_const_as(const float* p)
{ return (const CONSTANT_AS float*)(unsigned long long)p; }

// round-to-nearest-even high-half; pk2 packs {bf16(lo), bf16(hi)} (bit-exact
// vs round 7's form; v_perm_b32 takes S1[31:16]->D[15:0], S0[31:16]->D[31:16])
static __device__ __forceinline__ u32 rnd16(float f)
{
    const u32 u = __float_as_uint(f);
    return u + 0x7fffu + ((u >> 16) & 1u);
}
static __device__ __forceinline__ u32 pk2(float lo, float hi)
{ return __builtin_amdgcn_perm(rnd16(hi), rnd16(lo), 0x07060302u); }

// swap a's hi-32-lanes with b's lo-32-lanes: r.x = {a.lo, b.lo}, r.y = {a.hi, b.hi}
static __device__ __forceinline__ u32x2 plsw(u32 a, u32 b)
{ return __builtin_amdgcn_permlane32_swap(a, b, false, false); }

static __device__ __forceinline__ bf16x8 mkfrag(u32 w0, u32 w1, u32 w2, u32 w3)
{
    union { u32 u[4]; bf16x8 v; } c;
    c.u[0] = w0; c.u[1] = w1; c.u[2] = w2; c.u[3] = w3;
    return c.v;
}
static __device__ __forceinline__ bf16x8 u4frag(uint4 u)
{ union { uint4 a; bf16x8 v; } c; c.a = u; return c.v; }

static __device__ __forceinline__ f32x16 mfma(bf16x8 a, bf16x8 b, f32x16 c)
{ return __builtin_amdgcn_mfma_f32_32x32x16_bf16(a, b, c, 0, 0, 0); }

// stable softplus; 1+t in (1,2] -> __logf exact there (round-8 proven)
static __device__ __forceinline__ float softplus(float a)
{ return fmaxf(a, 0.0f) + __logf(1.0f + __expf(-fabsf(a))); }

// ---- setup kernel: layer-1 params at s_load-friendly stride (16 KB d_ws) ----

__global__ void pack_l1(const float* __restrict__ src, float* __restrict__ dst)
{
    const int b = blockIdx.x;
    const int t = threadIdx.x;
    if (t < L1N)
        dst[b * L1STRIDE + t] = src[(size_t)b * NPAR + t];
}

// ---- per-slot weight-fragment gather (mid layers only: f = 6L + 3t + s) ----

static __device__ __forceinline__ uint4 build_frag_slot(
    const float* __restrict__ pp, int f, int l)
{
    const int c31 = l & 31;
    const int g   = l >> 5;
    float tv[8];
#pragma unroll
    for (int j = 0; j < 8; ++j) tv[j] = 0.0f;

    const int L = f / 6, t = (f % 6) / 3, s = f % 3;
    const int wb = 108 + L * 1332;
    const int r  = c31 + 32 * t;                 // outfeat row
    if (r < 36) {
#pragma unroll
        for (int j = 0; j < 8; ++j) {
            const int i = 16 * s + 8 * g + j;    // infeat (k)
            if (i < 36)       tv[j] = pp[wb + 36 * r + i];
            else if (i == 36) tv[j] = pp[wb + 1296 + r];   // bias slot
        }
    }
    uint4 o;
    o.x = pk2(tv[0], tv[1]); o.y = pk2(tv[2], tv[3]);
    o.z = pk2(tv[4], tv[5]); o.w = pk2(tv[6], tv[7]);
    return o;
}

// ---- B-fragment builder: sin(D) -> next-layer B frag (12 words; proven) -----

static __device__ __forceinline__ void buildB(const f32x16& d1, const f32x16& d2,
                                              u32 biasw, u32 (&F)[12])
{
    float s1[16];
#pragma unroll
    for (int r = 0; r < 16; ++r) s1[r] = __sinf(d1[r]);
    u32 c[8];
#pragma unroll
    for (int q = 0; q < 8; ++q) c[q] = pk2(s1[2 * q], s1[2 * q + 1]);
    const u32 q0 = pk2(__sinf(d2[0]), __sinf(d2[1]));
    const u32 q1 = pk2(__sinf(d2[2]), __sinf(d2[3]));

    u32x2 r;
    r = plsw(c[0], c[2]); F[0] = r.x; F[2] = r.y;   // kstep0
    r = plsw(c[1], c[3]); F[1] = r.x; F[3] = r.y;
    r = plsw(c[4], c[6]); F[4] = r.x; F[6] = r.y;   // kstep1
    r = plsw(c[5], c[7]); F[5] = r.x; F[7] = r.y;
    F[8] = q0; F[9] = q1; F[10] = biasw; F[11] = 0; // kstep2
}

// ---- one point-tile through layers 2..4; returns softplus (valid lo lanes) --

static __device__ __forceinline__ float tile_forward(
    const uint4 (&W)[12], const u32 (&F)[12],
    const float (&w4a)[16], const float (&w4b)[4], float b4,
    u32 biasw, const f32x16& z)
{
    // layer 2 (frags 0..5)
    f32x16 d1 = z, d2 = z;
#pragma unroll
    for (int s = 0; s < 3; ++s) {
        const bf16x8 bf = mkfrag(F[4*s], F[4*s+1], F[4*s+2], F[4*s+3]);
        d1 = mfma(u4frag(W[s]),     bf, d1);
        d2 = mfma(u4frag(W[3 + s]), bf, d2);
    }
    // layer 3 (frags 6..11)
    u32 F2[12];
    buildB(d1, d2, biasw, F2);
    d1 = z; d2 = z;
#pragma unroll
    for (int s = 0; s < 3; ++s) {
        const bf16x8 bf = mkfrag(F2[4*s], F2[4*s+1], F2[4*s+2], F2[4*s+3]);
        d1 = mfma(u4frag(W[6 + s]), bf, d1);
        d2 = mfma(u4frag(W[9 + s]), bf, d2);
    }
    // final layer on VALU: sin#3 + f32 dot over this lane's feats
    float a0 = 0.0f, a1 = 0.0f;
#pragma unroll
    for (int r = 0; r < 16; r += 2) {
        a0 = fmaf(w4a[r],     __sinf(d1[r]),     a0);
        a1 = fmaf(w4a[r + 1], __sinf(d1[r + 1]), a1);
    }
#pragma unroll
    for (int r = 0; r < 4; r += 2) {
        a0 = fmaf(w4b[r],     __sinf(d2[r]),     a0);
        a1 = fmaf(w4b[r + 1], __sinf(d2[r + 1]), a1);
    }
    const float part = a0 + a1;
    // pair-reduce: lane l (<32) needs partner l+32's partial
    const u32x2 t = plsw(__float_as_uint(part), __float_as_uint(part));
    const float tot = part + __uint_as_float(t.y) + b4;
    return softplus(tot);
}

// ---- main kernel ------------------------------------------------------------

__global__ __launch_bounds__(256) void mlp_mfma_kernel(
    const float* __restrict__ x,
    const float* __restrict__ params,     // original (32,2809)
    const float* __restrict__ l1p,        // L1 params, stride 128
    float* __restrict__ out)
{
    __shared__ uint4 lds_fw[12 * 64];

    const int lane = threadIdx.x & 63;
    const int wave = threadIdx.x >> 6;
    const int b    = blockIdx.y;
    const int g    = lane >> 5;

    const float* pp = params + (size_t)b * NPAR;

    // ---- phase 0: cooperative frag build into LDS (once per block) ----
#pragma unroll
    for (int k = 0; k < 3; ++k) {
        const int sid = threadIdx.x + 256 * k;   // 0..767 == 12*64 exactly
        lds_fw[sid] = build_frag_slot(pp, sid >> 6, sid & 63);
    }
    __syncthreads();

    uint4 W[12];
#pragma unroll
    for (int f = 0; f < 12; ++f)
        W[f] = lds_fw[f * 64 + lane];

    // ---- per-lane W4 in f32, feat mapping (r&3)+8*(r>>2)+4g / 32+r+4g ----
    float w4a[16];
#pragma unroll
    for (int r = 0; r < 16; ++r)
        w4a[r] = pp[2772 + ((r & 3) + 8 * (r >> 2) + 4 * g)];
    float w4b[4];
#pragma unroll
    for (int r = 0; r < 4; ++r)
        w4b[r] = (g == 0) ? pp[2772 + 32 + r] : 0.0f;
    const float b4 = pp[2808];

    const CONSTANT_AS float* pc = to_const_as(l1p + (size_t)b * L1STRIDE);
    const u32 biasw = pk2(1.0f, 0.0f);

    f32x16 z;
#pragma unroll
    for (int i = 0; i < 16; ++i) z[i] = 0.0f;

#pragma unroll 1
    for (int it = 0; it < 4; ++it) {
        const int n = blockIdx.x * 1024 + wave * 256 + it * 64 + lane;
        const float2 xv = reinterpret_cast<const float2*>(x)[n];

        // ---- layer 1 on VALU (lane = point): 36 feats -> 18 bf16x2 words
        u32 hw[18];
#pragma unroll
        for (int o2 = 0; o2 < 18; ++o2) {
            const float a0 = fmaf(pc[4 * o2 + 0], xv.x,
                             fmaf(pc[4 * o2 + 1], xv.y, pc[72 + 2 * o2 + 0]));
            const float a1 = fmaf(pc[4 * o2 + 2], xv.x,
                             fmaf(pc[4 * o2 + 3], xv.y, pc[72 + 2 * o2 + 1]));
            hw[o2] = pk2(__sinf(a0), __sinf(a1));
        }

        // ---- both point-tile B frags from layer-1 output (10 swaps)
        u32 FA[12], FB[12];
#pragma unroll
        for (int q = 0; q < 4; ++q) {
            u32x2 r0 = plsw(hw[q],     hw[4 + q]);  FA[q]     = r0.x; FB[q]     = r0.y;
            u32x2 r1 = plsw(hw[8 + q], hw[12 + q]); FA[4 + q] = r1.x; FB[4 + q] = r1.y;
        }
        FA[8] = hw[16]; FA[9] = hw[17];
        { u32x2 r = plsw(hw[16], hw[16]); FB[8] = r.y; }
        { u32x2 r = plsw(hw[17], hw[17]); FB[9] = r.y; }
        FA[10] = biasw; FA[11] = 0; FB[10] = biasw; FB[11] = 0;

        // ---- tiles serially (small live accumulator set)
        const float spA = tile_forward(W, FA, w4a, w4b, b4, biasw, z);
        const float spB = tile_forward(W, FB, w4a, w4b, b4, biasw, z);

        // ---- merged store (tile A -> lanes 0..31, B -> 32..63)
        const u32x2 r = plsw(__float_as_uint(spA), __float_as_uint(spB));
        out[(size_t)b * NPTS + n] = __uint_as_float(r.x);
    }
}

extern "C" void kernel_launch(void* const* d_in, const int* in_sizes, int n_in,
                              void* d_out, int out_size, void* d_ws, size_t ws_size,
                              hipStream_t stream)
{
    const float* x = (const float*)d_in[0];
    const float* params = (const float*)d_in[1];
    float* out = (float*)d_out;
    float* l1p = (float*)d_ws;   // 32*128*4 = 16,384 B — inside proven ws use

    pack_l1<<<dim3(NBATCH), dim3(128), 0, stream>>>(params, l1p);

    mlp_mfma_kernel<<<dim3(NPTS / 1024, NBATCH), dim3(256), 0, stream>>>(
        x, params, l1p, out);
}

// Round 10
// 58.788 us; speedup vs baseline: 4.3308x; 1.1076x over previous
//
#include <hip/hip_runtime.h>
#include <math.h>

// Per-batch MLP 2->36->36->36->1 (sin,sin,sin,softplus) on MFMA, round 10.
// x: (65536,2) f32; params: (32,2809) f32; out: (32,65536) f32.
//
// Formulation per 32-point tile: D = W * h^T, v_mfma_f32_32x32x16_bf16.
//   A = W (M=outfeat pad 64 -> 2 tiles), B = h^T (N=32 points),
//   bias folded at k==36 (mid layers) / k==2 (layer 1) with h=1.0.
// D layout (HW-verified): col=lane&31 (point), feat=(r&3)+8*(r>>2)+4*(lane>>5).
//
// Round-10: LAYER 1 ONTO MFMA. Round 9 still re-s_loaded 108 L1 floats per
// iteration through constant-AS (SGPR=112 at cap -> nothing stays resident;
// out-of-order SMEM => lgkmcnt(0) drains = the ~27% non-busy time). L1 is a
// K=3 matmul: A-frag k=0:wx, k=1:wy, k=2:b1, k>=3:0 (built in the proven
// frag-build path); B-frag = {pk2(x,y), biasw, 0, 0}. Don't-care k-slots need
// NO masking: the matching A entries are exactly zero and B words are finite.
// Tile-B's B-frag is one permlane32_swap. L1-D feeds the PROVEN buildB.
// Deletes per-iter: 72 fma, 18 pk2, 10-plsw hw->F block, all scalar loads
// and their stalls, plus the pack_l1 kernel (d_ws now unused).
// Frozen: software-RNE pk2 (bit-exact), __sinf radians, plsw exchanges,
// per-block LDS frag build (now 14 frags = 14,336 B), serial tiles,
// final layer on VALU in f32.
// New numeric exposure (flagged): L1 weights & x now bf16 into MFMA
// (~2e-3 rad preact error) -- absmax may tick up, budget << 0.017.

#define NPTS   65536
#define NBATCH 32
#define NPAR   2809

typedef float        f32x16 __attribute__((ext_vector_type(16)));
typedef short        bf16x8 __attribute__((ext_vector_type(8)));
typedef unsigned int u32;
typedef unsigned int u32x2 __attribute__((ext_vector_type(2)));

// round-to-nearest-even high-half; pk2 packs {bf16(lo), bf16(hi)} (bit-exact
// vs round 7; v_perm_b32 takes S1[31:16]->D[15:0], S0[31:16]->D[31:16])
static __device__ __forceinline__ u32 rnd16(float f)
{
    const u32 u = __float_as_uint(f);
    return u + 0x7fffu + ((u >> 16) & 1u);
}
static __device__ __forceinline__ u32 pk2(float lo, float hi)
{ return __builtin_amdgcn_perm(rnd16(hi), rnd16(lo), 0x07060302u); }

// swap a's hi-32-lanes with b's lo-32-lanes (proven in rounds 6-9):
// r.x = {a.lo, b.lo-moved-up}, r.y = {a.hi-moved-down, b.hi}
static __device__ __forceinline__ u32x2 plsw(u32 a, u32 b)
{ return __builtin_amdgcn_permlane32_swap(a, b, false, false); }

static __device__ __forceinline__ bf16x8 mkfrag(u32 w0, u32 w1, u32 w2, u32 w3)
{
    union { u32 u[4]; bf16x8 v; } c;
    c.u[0] = w0; c.u[1] = w1; c.u[2] = w2; c.u[3] = w3;
    return c.v;
}
static __device__ __forceinline__ bf16x8 u4frag(uint4 u)
{ union { uint4 a; bf16x8 v; } c; c.a = u; return c.v; }

static __device__ __forceinline__ f32x16 mfma(bf16x8 a, bf16x8 b, f32x16 c)
{ return __builtin_amdgcn_mfma_f32_32x32x16_bf16(a, b, c, 0, 0, 0); }

// stable softplus; 1+t in (1,2] -> __logf exact there (round-8 proven)
static __device__ __forceinline__ float softplus(float a)
{ return fmaxf(a, 0.0f) + __logf(1.0f + __expf(-fabsf(a))); }

// ---- per-slot weight-fragment gather ---------------------------------------
// Frag ids: mid layers f = 6L + 3t + s (L=layer, t=feat-tile, s=kstep);
// f = 12+t: layer-1 W1 feat-tile t (single kstep, k=0:wx,1:wy,2:b1).

static __device__ __forceinline__ uint4 build_frag_slot(
    const float* __restrict__ pp, int f, int l)
{
    const int c31 = l & 31;
    const int g   = l >> 5;
    float tv[8];
#pragma unroll
    for (int j = 0; j < 8; ++j) tv[j] = 0.0f;

    if (f < 12) {
        const int L = f / 6, t = (f % 6) / 3, s = f % 3;
        const int wb = 108 + L * 1332;
        const int r  = c31 + 32 * t;                 // outfeat row
        if (r < 36) {
#pragma unroll
            for (int j = 0; j < 8; ++j) {
                const int i = 16 * s + 8 * g + j;    // infeat (k)
                if (i < 36)       tv[j] = pp[wb + 36 * r + i];
                else if (i == 36) tv[j] = pp[wb + 1296 + r];   // bias slot
            }
        }
    } else {
        const int t = f - 12;                        // layer-1 tile
        const int r = c31 + 32 * t;
        if (r < 36 && g == 0) {
            tv[0] = pp[2 * r];          // k=0: w_x
            tv[1] = pp[2 * r + 1];      // k=1: w_y
            tv[2] = pp[72 + r];         // k=2: bias (h=1 slot)
            // k=3..7 stay 0; g1 half (k=8..15) all 0
        }
    }
    uint4 o;
    o.x = pk2(tv[0], tv[1]); o.y = pk2(tv[2], tv[3]);
    o.z = pk2(tv[4], tv[5]); o.w = pk2(tv[6], tv[7]);
    return o;
}

// ---- B-fragment builder: sin(D) -> next-layer B frag (12 words; proven) -----

static __device__ __forceinline__ void buildB(const f32x16& d1, const f32x16& d2,
                                              u32 biasw, u32 (&F)[12])
{
    float s1[16];
#pragma unroll
    for (int r = 0; r < 16; ++r) s1[r] = __sinf(d1[r]);
    u32 c[8];
#pragma unroll
    for (int q = 0; q < 8; ++q) c[q] = pk2(s1[2 * q], s1[2 * q + 1]);
    const u32 q0 = pk2(__sinf(d2[0]), __sinf(d2[1]));
    const u32 q1 = pk2(__sinf(d2[2]), __sinf(d2[3]));

    u32x2 r;
    r = plsw(c[0], c[2]); F[0] = r.x; F[2] = r.y;   // kstep0
    r = plsw(c[1], c[3]); F[1] = r.x; F[3] = r.y;
    r = plsw(c[4], c[6]); F[4] = r.x; F[6] = r.y;   // kstep1
    r = plsw(c[5], c[7]); F[5] = r.x; F[7] = r.y;
    F[8] = q0; F[9] = q1; F[10] = biasw; F[11] = 0; // kstep2
}

// ---- one point-tile: L1 mfma -> L2 -> L3 -> final on VALU -------------------

static __device__ __forceinline__ float tile_forward(
    const uint4 (&W)[12], bf16x8 w1a, bf16x8 w1b, bf16x8 bl1,
    const float (&w4a)[16], const float (&w4b)[4], float b4,
    u32 biasw, const f32x16& z)
{
    // layer 1 (K=3 in one kstep)
    f32x16 d1 = mfma(w1a, bl1, z);
    f32x16 d2 = mfma(w1b, bl1, z);

    // layer 2 (frags 0..5)
    u32 F[12];
    buildB(d1, d2, biasw, F);
    d1 = z; d2 = z;
#pragma unroll
    for (int s = 0; s < 3; ++s) {
        const bf16x8 bf = mkfrag(F[4*s], F[4*s+1], F[4*s+2], F[4*s+3]);
        d1 = mfma(u4frag(W[s]),     bf, d1);
        d2 = mfma(u4frag(W[3 + s]), bf, d2);
    }
    // layer 3 (frags 6..11)
    u32 F2[12];
    buildB(d1, d2, biasw, F2);
    d1 = z; d2 = z;
#pragma unroll
    for (int s = 0; s < 3; ++s) {
        const bf16x8 bf = mkfrag(F2[4*s], F2[4*s+1], F2[4*s+2], F2[4*s+3]);
        d1 = mfma(u4frag(W[6 + s]), bf, d1);
        d2 = mfma(u4frag(W[9 + s]), bf, d2);
    }
    // final layer on VALU: sin#3 + f32 dot over this lane's feats
    float a0 = 0.0f, a1 = 0.0f;
#pragma unroll
    for (int r = 0; r < 16; r += 2) {
        a0 = fmaf(w4a[r],     __sinf(d1[r]),     a0);
        a1 = fmaf(w4a[r + 1], __sinf(d1[r + 1]), a1);
    }
#pragma unroll
    for (int r = 0; r < 4; r += 2) {
        a0 = fmaf(w4b[r],     __sinf(d2[r]),     a0);
        a1 = fmaf(w4b[r + 1], __sinf(d2[r + 1]), a1);
    }
    const float part = a0 + a1;
    // pair-reduce: lane l (<32) adds partner l+32's partial
    const u32x2 t = plsw(__float_as_uint(part), __float_as_uint(part));
    const float tot = part + __uint_as_float(t.y) + b4;
    return softplus(tot);   // valid at g0 lanes
}

// ---- main kernel ------------------------------------------------------------

__global__ __launch_bounds__(256) void mlp_mfma_kernel(
    const float* __restrict__ x,
    const float* __restrict__ params,     // original (32,2809)
    float* __restrict__ out)
{
    __shared__ uint4 lds_fw[14 * 64];

    const int lane = threadIdx.x & 63;
    const int wave = threadIdx.x >> 6;
    const int b    = blockIdx.y;
    const int g    = lane >> 5;

    const float* pp = params + (size_t)b * NPAR;

    // ---- phase 0: cooperative frag build into LDS (once per block) ----
#pragma unroll
    for (int k = 0; k < 4; ++k) {
        const int sid = threadIdx.x + 256 * k;   // 0..1023; 896 real slots
        if (sid < 896)
            lds_fw[sid] = build_frag_slot(pp, sid >> 6, sid & 63);
    }
    __syncthreads();

    uint4 W[12];
#pragma unroll
    for (int f = 0; f < 12; ++f)
        W[f] = lds_fw[f * 64 + lane];
    const bf16x8 w1a = u4frag(lds_fw[12 * 64 + lane]);
    const bf16x8 w1b = u4frag(lds_fw[13 * 64 + lane]);

    // ---- per-lane W4 in f32, feat mapping (r&3)+8*(r>>2)+4g / 32+r+4g ----
    float w4a[16];
#pragma unroll
    for (int r = 0; r < 16; ++r)
        w4a[r] = pp[2772 + ((r & 3) + 8 * (r >> 2) + 4 * g)];
    float w4b[4];
#pragma unroll
    for (int r = 0; r < 4; ++r)
        w4b[r] = (g == 0) ? pp[2772 + 32 + r] : 0.0f;
    const float b4 = pp[2808];

    const u32 biasw = pk2(1.0f, 0.0f);

    f32x16 z;
#pragma unroll
    for (int i = 0; i < 16; ++i) z[i] = 0.0f;

#pragma unroll 1
    for (int it = 0; it < 4; ++it) {
        const int n = blockIdx.x * 1024 + wave * 256 + it * 64 + lane;
        const float2 xv = reinterpret_cast<const float2*>(x)[n];

        // layer-1 B frags: own point (tile A) / partner's point (tile B).
        // g1 lanes' words sit at k-slots where W1 frag is exactly 0 -> no mask.
        const u32 pxy  = pk2(xv.x, xv.y);
        const u32 pxyB = plsw(pxy, pxy).y;

        const float spA = tile_forward(W, w1a, w1b, mkfrag(pxy,  biasw, 0, 0),
                                       w4a, w4b, b4, biasw, z);
        const float spB = tile_forward(W, w1a, w1b, mkfrag(pxyB, biasw, 0, 0),
                                       w4a, w4b, b4, biasw, z);

        // merged store (tile A -> lanes 0..31, tile B -> lanes 32..63)
        const u32x2 r = plsw(__float_as_uint(spA), __float_as_uint(spB));
        out[(size_t)b * NPTS + n] = __uint_as_float(r.x);
    }
}

extern "C" void kernel_launch(void* const* d_in, const int* in_sizes, int n_in,
                              void* d_out, int out_size, void* d_ws, size_t ws_size,
                              hipStream_t stream)
{
    const float* x = (const float*)d_in[0];
    const float* params = (const float*)d_in[1];
    float* out = (float*)d_out;

    mlp_mfma_kernel<<<dim3(NPTS / 1024, NBATCH), dim3(256), 0, stream>>>(
        x, params, out);
}

// Round 12
// 50.920 us; speedup vs baseline: 5.0000x; 1.1545x over previous
//
#include <hip/hip_runtime.h>
#include <math.h>

// Per-batch MLP 2->36->36->36->1 (sin,sin,sin,softplus) on MFMA, round 12.
// x: (65536,2) f32; params: (32,2809) f32; out: (32,65536) f32.
//
// Formulation per 32-point tile: D = W * h^T, v_mfma_f32_32x32x16_bf16.
//   A = W (M=outfeat pad 64 -> 2 tiles), B = h^T (N=32 points),
//   bias folded at k==36 (mid layers) / k==2 (layer 1) with h=1.0.
// D layout (HW-verified): col=lane&31 (point), feat=(r&3)+8*(r>>2)+4*(lane>>5).
//
// Round-12. v_cvt_pk_bf16_f32 VERDICT: condemned. 3-for-3 failures when
// present (r5 0.35 / r6 0.098 / r11 NaN) vs 4-for-4 clean without (r7-r10);
// varying signatures = semantics not understood in this context. Never again.
// This round, two deltas with DISJOINT failure signatures vs proven round 10:
//  (1) ITERS=8 retained (phase-0 LDS-build amortization; value-identical
//      indexing). A NaN failure would implicate this -> revert next round.
//  (2) pk2 -> 1-inst RTZ pack: v_perm_b32 of the two f32 high halves
//      (truncation). v_perm is proven (was inside the 5-inst RNE pk2);
//      truncation of finite values cannot make NaN/Inf, so a failure shows
//      ONLY as finite absmax growth (predicted ~0.006-0.010 vs thr 0.017).
//      Saves ~160 VALU inst/iter.
// Frozen: __sinf radians, plsw exchanges, LDS frag build, serial tiles,
// final layer on VALU in f32, softplus form.

#define NPTS   65536
#define NBATCH 32
#define NPAR   2809
#define ITERS  8       // points per wave = 64 * ITERS

typedef float        f32x16 __attribute__((ext_vector_type(16)));
typedef short        bf16x8 __attribute__((ext_vector_type(8)));
typedef unsigned int u32;
typedef unsigned int u32x2 __attribute__((ext_vector_type(2)));

// 1-inst pack {bf16_rtz(lo), bf16_rtz(hi)}: v_perm_b32 selects
// S1[31:16] -> D[15:0] and S0[31:16] -> D[31:16]  (S0=hi bits, S1=lo bits).
static __device__ __forceinline__ u32 pk2(float lo, float hi)
{
    return __builtin_amdgcn_perm(__float_as_uint(hi), __float_as_uint(lo),
                                 0x07060302u);
}

// swap a's hi-32-lanes with b's lo-32-lanes (proven rounds 6-10):
// r.x = {a.lo, b.lo-moved-up}, r.y = {a.hi-moved-down, b.hi}
static __device__ __forceinline__ u32x2 plsw(u32 a, u32 b)
{ return __builtin_amdgcn_permlane32_swap(a, b, false, false); }

static __device__ __forceinline__ bf16x8 mkfrag(u32 w0, u32 w1, u32 w2, u32 w3)
{
    union { u32 u[4]; bf16x8 v; } c;
    c.u[0] = w0; c.u[1] = w1; c.u[2] = w2; c.u[3] = w3;
    return c.v;
}
static __device__ __forceinline__ bf16x8 u4frag(uint4 u)
{ union { uint4 a; bf16x8 v; } c; c.a = u; return c.v; }

static __device__ __forceinline__ f32x16 mfma(bf16x8 a, bf16x8 b, f32x16 c)
{ return __builtin_amdgcn_mfma_f32_32x32x16_bf16(a, b, c, 0, 0, 0); }

// stable softplus; 1+t in (1,2] -> __logf exact there (round-8 proven)
static __device__ __forceinline__ float softplus(float a)
{ return fmaxf(a, 0.0f) + __logf(1.0f + __expf(-fabsf(a))); }

// ---- per-slot weight-fragment gather ---------------------------------------
// Frag ids: mid layers f = 6L + 3t + s (L=layer, t=feat-tile, s=kstep);
// f = 12+t: layer-1 W1 feat-tile t (single kstep, k=0:wx,1:wy,2:b1).

static __device__ __forceinline__ uint4 build_frag_slot(
    const float* __restrict__ pp, int f, int l)
{
    const int c31 = l & 31;
    const int g   = l >> 5;
    float tv[8];
#pragma unroll
    for (int j = 0; j < 8; ++j) tv[j] = 0.0f;

    if (f < 12) {
        const int L = f / 6, t = (f % 6) / 3, s = f % 3;
        const int wb = 108 + L * 1332;
        const int r  = c31 + 32 * t;                 // outfeat row
        if (r < 36) {
#pragma unroll
            for (int j = 0; j < 8; ++j) {
                const int i = 16 * s + 8 * g + j;    // infeat (k)
                if (i < 36)       tv[j] = pp[wb + 36 * r + i];
                else if (i == 36) tv[j] = pp[wb + 1296 + r];   // bias slot
            }
        }
    } else {
        const int t = f - 12;                        // layer-1 tile
        const int r = c31 + 32 * t;
        if (r < 36 && g == 0) {
            tv[0] = pp[2 * r];          // k=0: w_x
            tv[1] = pp[2 * r + 1];      // k=1: w_y
            tv[2] = pp[72 + r];         // k=2: bias (h=1 slot)
        }
    }
    uint4 o;
    o.x = pk2(tv[0], tv[1]); o.y = pk2(tv[2], tv[3]);
    o.z = pk2(tv[4], tv[5]); o.w = pk2(tv[6], tv[7]);
    return o;
}

// ---- B-fragment builder: sin(D) -> next-layer B frag (12 words; proven) -----

static __device__ __forceinline__ void buildB(const f32x16& d1, const f32x16& d2,
                                              u32 biasw, u32 (&F)[12])
{
    float s1[16];
#pragma unroll
    for (int r = 0; r < 16; ++r) s1[r] = __sinf(d1[r]);
    u32 c[8];
#pragma unroll
    for (int q = 0; q < 8; ++q) c[q] = pk2(s1[2 * q], s1[2 * q + 1]);
    const u32 q0 = pk2(__sinf(d2[0]), __sinf(d2[1]));
    const u32 q1 = pk2(__sinf(d2[2]), __sinf(d2[3]));

    u32x2 r;
    r = plsw(c[0], c[2]); F[0] = r.x; F[2] = r.y;   // kstep0
    r = plsw(c[1], c[3]); F[1] = r.x; F[3] = r.y;
    r = plsw(c[4], c[6]); F[4] = r.x; F[6] = r.y;   // kstep1
    r = plsw(c[5], c[7]); F[5] = r.x; F[7] = r.y;
    F[8] = q0; F[9] = q1; F[10] = biasw; F[11] = 0; // kstep2
}

// ---- one point-tile: L1 mfma -> L2 -> L3 -> final on VALU -------------------

static __device__ __forceinline__ float tile_forward(
    const uint4 (&W)[12], bf16x8 w1a, bf16x8 w1b, bf16x8 bl1,
    const float (&w4a)[16], const float (&w4b)[4], float b4,
    u32 biasw, const f32x16& z)
{
    // layer 1 (K=3 in one kstep)
    f32x16 d1 = mfma(w1a, bl1, z);
    f32x16 d2 = mfma(w1b, bl1, z);

    // layer 2 (frags 0..5)
    u32 F[12];
    buildB(d1, d2, biasw, F);
    d1 = z; d2 = z;
#pragma unroll
    for (int s = 0; s < 3; ++s) {
        const bf16x8 bf = mkfrag(F[4*s], F[4*s+1], F[4*s+2], F[4*s+3]);
        d1 = mfma(u4frag(W[s]),     bf, d1);
        d2 = mfma(u4frag(W[3 + s]), bf, d2);
    }
    // layer 3 (frags 6..11)
    u32 F2[12];
    buildB(d1, d2, biasw, F2);
    d1 = z; d2 = z;
#pragma unroll
    for (int s = 0; s < 3; ++s) {
        const bf16x8 bf = mkfrag(F2[4*s], F2[4*s+1], F2[4*s+2], F2[4*s+3]);
        d1 = mfma(u4frag(W[6 + s]), bf, d1);
        d2 = mfma(u4frag(W[9 + s]), bf, d2);
    }
    // final layer on VALU: sin#3 + f32 dot over this lane's feats
    float a0 = 0.0f, a1 = 0.0f;
#pragma unroll
    for (int r = 0; r < 16; r += 2) {
        a0 = fmaf(w4a[r],     __sinf(d1[r]),     a0);
        a1 = fmaf(w4a[r + 1], __sinf(d1[r + 1]), a1);
    }
#pragma unroll
    for (int r = 0; r < 4; r += 2) {
        a0 = fmaf(w4b[r],     __sinf(d2[r]),     a0);
        a1 = fmaf(w4b[r + 1], __sinf(d2[r + 1]), a1);
    }
    const float part = a0 + a1;
    // pair-reduce: lane l (<32) adds partner l+32's partial
    const u32x2 t = plsw(__float_as_uint(part), __float_as_uint(part));
    const float tot = part + __uint_as_float(t.y) + b4;
    return softplus(tot);   // valid at g0 lanes
}

// ---- main kernel ------------------------------------------------------------

__global__ __launch_bounds__(256) void mlp_mfma_kernel(
    const float* __restrict__ x,
    const float* __restrict__ params,     // original (32,2809)
    float* __restrict__ out)
{
    __shared__ uint4 lds_fw[14 * 64];

    const int lane = threadIdx.x & 63;
    const int wave = threadIdx.x >> 6;
    const int b    = blockIdx.y;
    const int g    = lane >> 5;

    const float* pp = params + (size_t)b * NPAR;

    // ---- phase 0: cooperative frag build into LDS (once per block) ----
#pragma unroll
    for (int k = 0; k < 4; ++k) {
        const int sid = threadIdx.x + 256 * k;   // 0..1023; 896 real slots
        if (sid < 896)
            lds_fw[sid] = build_frag_slot(pp, sid >> 6, sid & 63);
    }
    __syncthreads();

    uint4 W[12];
#pragma unroll
    for (int f = 0; f < 12; ++f)
        W[f] = lds_fw[f * 64 + lane];
    const bf16x8 w1a = u4frag(lds_fw[12 * 64 + lane]);
    const bf16x8 w1b = u4frag(lds_fw[13 * 64 + lane]);

    // ---- per-lane W4 in f32, feat mapping (r&3)+8*(r>>2)+4g / 32+r+4g ----
    float w4a[16];
#pragma unroll
    for (int r = 0; r < 16; ++r)
        w4a[r] = pp[2772 + ((r & 3) + 8 * (r >> 2) + 4 * g)];
    float w4b[4];
#pragma unroll
    for (int r = 0; r < 4; ++r)
        w4b[r] = (g == 0) ? pp[2772 + 32 + r] : 0.0f;
    const float b4 = pp[2808];

    const u32 biasw = pk2(1.0f, 0.0f);

    f32x16 z;
#pragma unroll
    for (int i = 0; i < 16; ++i) z[i] = 0.0f;

#pragma unroll 1
    for (int it = 0; it < ITERS; ++it) {
        const int n = blockIdx.x * (64 * ITERS * 4) + wave * (64 * ITERS)
                    + it * 64 + lane;
        const float2 xv = reinterpret_cast<const float2*>(x)[n];

        // layer-1 B frags: own point (tile A) / partner's point (tile B).
        // g1 lanes' words sit at k-slots where W1 frag is exactly 0 -> no mask.
        const u32 pxy  = pk2(xv.x, xv.y);
        const u32 pxyB = plsw(pxy, pxy).y;

        const float spA = tile_forward(W, w1a, w1b, mkfrag(pxy,  biasw, 0, 0),
                                       w4a, w4b, b4, biasw, z);
        const float spB = tile_forward(W, w1a, w1b, mkfrag(pxyB, biasw, 0, 0),
                                       w4a, w4b, b4, biasw, z);

        // merged store (tile A -> lanes 0..31, tile B -> lanes 32..63)
        const u32x2 r = plsw(__float_as_uint(spA), __float_as_uint(spB));
        out[(size_t)b * NPTS + n] = __uint_as_float(r.x);
    }
}

extern "C" void kernel_launch(void* const* d_in, const int* in_sizes, int n_in,
                              void* d_out, int out_size, void* d_ws, size_t ws_size,
                              hipStream_t stream)
{
    const float* x = (const float*)d_in[0];
    const float* params = (const float*)d_in[1];
    float* out = (float*)d_out;

    mlp_mfma_kernel<<<dim3(NPTS / (64 * ITERS * 4), NBATCH), dim3(256), 0, stream>>>(
        x, params, out);
}

// Round 13
// 46.823 us; speedup vs baseline: 5.4375x; 1.0875x over previous
//
#include <hip/hip_runtime.h>
#include <math.h>

// Per-batch MLP 2->36->36->36->1 (sin,sin,sin,softplus) on MFMA, round 13.
// x: (65536,2) f32; params: (32,2809) f32; out: (32,65536) f32.
//
// Formulation per 32-point tile: D = W * h^T, v_mfma_f32_32x32x16_bf16.
//   A = W (M=outfeat pad 64 -> 2 tiles), B = h^T (N=32 points),
//   bias folded at k==36 (mid layers) / k==2 (layer 1) with h=1.0.
// D layout (HW-verified): col=lane&31 (point), feat=(r&3)+8*(r>>2)+4*(lane>>5).
//
// Round-13: SINGLE-VARIABLE test of the 1/(2pi) sin-fold (never isolated;
// r6 bundled it with the now-independently-condemned cvt_pk). Fold INV2PI
// into W1,b1,W2,b2,W3,b3 at frag-build time; every __sinf (v_mul + v_sin)
// becomes raw v_sin in revolutions (__builtin_amdgcn_sinf). W4/b4 unfolded
// (softplus path). Numerics: bf16 relative quant error is scale-invariant
// (w/2pi quantizes with the same 2^-9 rel error as w); |preact| <= ~0.65 rev
// inside v_sin range -> absmax predicted ~0.004-0.008. Saves 120 v_mul/iter.
// Failure decode: O(1) absmax => fold semantics wrong, revert permanently.
// Frozen: RTZ pk2 (r12-proven), plsw exchanges, LDS frag build, ITERS=8,
// serial tiles, final layer on VALU in f32, softplus form. cvt_pk: never.

#define NPTS   65536
#define NBATCH 32
#define NPAR   2809
#define ITERS  8       // points per wave = 64 * ITERS
#define INV2PI 0.15915494309189535f

typedef float        f32x16 __attribute__((ext_vector_type(16)));
typedef short        bf16x8 __attribute__((ext_vector_type(8)));
typedef unsigned int u32;
typedef unsigned int u32x2 __attribute__((ext_vector_type(2)));

// 1-inst pack {bf16_rtz(lo), bf16_rtz(hi)} (r12-proven): v_perm_b32 selects
// S1[31:16] -> D[15:0] and S0[31:16] -> D[31:16]  (S0=hi bits, S1=lo bits).
static __device__ __forceinline__ u32 pk2(float lo, float hi)
{
    return __builtin_amdgcn_perm(__float_as_uint(hi), __float_as_uint(lo),
                                 0x07060302u);
}

// raw v_sin_f32: sin(2*pi*y), y in revolutions (|y| <= ~0.65 here)
static __device__ __forceinline__ float sin_rev(float y)
{ return __builtin_amdgcn_sinf(y); }

// swap a's hi-32-lanes with b's lo-32-lanes (proven rounds 6-12):
// r.x = {a.lo, b.lo-moved-up}, r.y = {a.hi-moved-down, b.hi}
static __device__ __forceinline__ u32x2 plsw(u32 a, u32 b)
{ return __builtin_amdgcn_permlane32_swap(a, b, false, false); }

static __device__ __forceinline__ bf16x8 mkfrag(u32 w0, u32 w1, u32 w2, u32 w3)
{
    union { u32 u[4]; bf16x8 v; } c;
    c.u[0] = w0; c.u[1] = w1; c.u[2] = w2; c.u[3] = w3;
    return c.v;
}
static __device__ __forceinline__ bf16x8 u4frag(uint4 u)
{ union { uint4 a; bf16x8 v; } c; c.a = u; return c.v; }

static __device__ __forceinline__ f32x16 mfma(bf16x8 a, bf16x8 b, f32x16 c)
{ return __builtin_amdgcn_mfma_f32_32x32x16_bf16(a, b, c, 0, 0, 0); }

// stable softplus; 1+t in (1,2] -> __logf exact there (round-8 proven)
static __device__ __forceinline__ float softplus(float a)
{ return fmaxf(a, 0.0f) + __logf(1.0f + __expf(-fabsf(a))); }

// ---- per-slot weight-fragment gather ---------------------------------------
// Frag ids: mid layers f = 6L + 3t + s (L=layer, t=feat-tile, s=kstep);
// f = 12+t: layer-1 W1 feat-tile t (single kstep, k=0:wx,1:wy,2:b1).
// ALL sin-layer weights/biases scaled by INV2PI (round-13 fold).

static __device__ __forceinline__ uint4 build_frag_slot(
    const float* __restrict__ pp, int f, int l)
{
    const int c31 = l & 31;
    const int g   = l >> 5;
    float tv[8];
#pragma unroll
    for (int j = 0; j < 8; ++j) tv[j] = 0.0f;

    if (f < 12) {
        const int L = f / 6, t = (f % 6) / 3, s = f % 3;
        const int wb = 108 + L * 1332;
        const int r  = c31 + 32 * t;                 // outfeat row
        if (r < 36) {
#pragma unroll
            for (int j = 0; j < 8; ++j) {
                const int i = 16 * s + 8 * g + j;    // infeat (k)
                if (i < 36)       tv[j] = pp[wb + 36 * r + i] * INV2PI;
                else if (i == 36) tv[j] = pp[wb + 1296 + r] * INV2PI;  // bias
            }
        }
    } else {
        const int t = f - 12;                        // layer-1 tile
        const int r = c31 + 32 * t;
        if (r < 36 && g == 0) {
            tv[0] = pp[2 * r]     * INV2PI;   // k=0: w_x
            tv[1] = pp[2 * r + 1] * INV2PI;   // k=1: w_y
            tv[2] = pp[72 + r]    * INV2PI;   // k=2: bias (h=1 slot)
        }
    }
    uint4 o;
    o.x = pk2(tv[0], tv[1]); o.y = pk2(tv[2], tv[3]);
    o.z = pk2(tv[4], tv[5]); o.w = pk2(tv[6], tv[7]);
    return o;
}

// ---- B-fragment builder: sin(D) -> next-layer B frag (12 words) -------------
// D is in REVOLUTIONS (weights folded); sin_rev = raw v_sin.

static __device__ __forceinline__ void buildB(const f32x16& d1, const f32x16& d2,
                                              u32 biasw, u32 (&F)[12])
{
    float s1[16];
#pragma unroll
    for (int r = 0; r < 16; ++r) s1[r] = sin_rev(d1[r]);
    u32 c[8];
#pragma unroll
    for (int q = 0; q < 8; ++q) c[q] = pk2(s1[2 * q], s1[2 * q + 1]);
    const u32 q0 = pk2(sin_rev(d2[0]), sin_rev(d2[1]));
    const u32 q1 = pk2(sin_rev(d2[2]), sin_rev(d2[3]));

    u32x2 r;
    r = plsw(c[0], c[2]); F[0] = r.x; F[2] = r.y;   // kstep0
    r = plsw(c[1], c[3]); F[1] = r.x; F[3] = r.y;
    r = plsw(c[4], c[6]); F[4] = r.x; F[6] = r.y;   // kstep1
    r = plsw(c[5], c[7]); F[5] = r.x; F[7] = r.y;
    F[8] = q0; F[9] = q1; F[10] = biasw; F[11] = 0; // kstep2
}

// ---- one point-tile: L1 mfma -> L2 -> L3 -> final on VALU -------------------

static __device__ __forceinline__ float tile_forward(
    const uint4 (&W)[12], bf16x8 w1a, bf16x8 w1b, bf16x8 bl1,
    const float (&w4a)[16], const float (&w4b)[4], float b4,
    u32 biasw, const f32x16& z)
{
    // layer 1 (K=3 in one kstep); D in revolutions
    f32x16 d1 = mfma(w1a, bl1, z);
    f32x16 d2 = mfma(w1b, bl1, z);

    // layer 2 (frags 0..5)
    u32 F[12];
    buildB(d1, d2, biasw, F);
    d1 = z; d2 = z;
#pragma unroll
    for (int s = 0; s < 3; ++s) {
        const bf16x8 bf = mkfrag(F[4*s], F[4*s+1], F[4*s+2], F[4*s+3]);
        d1 = mfma(u4frag(W[s]),     bf, d1);
        d2 = mfma(u4frag(W[3 + s]), bf, d2);
    }
    // layer 3 (frags 6..11)
    u32 F2[12];
    buildB(d1, d2, biasw, F2);
    d1 = z; d2 = z;
#pragma unroll
    for (int s = 0; s < 3; ++s) {
        const bf16x8 bf = mkfrag(F2[4*s], F2[4*s+1], F2[4*s+2], F2[4*s+3]);
        d1 = mfma(u4frag(W[6 + s]), bf, d1);
        d2 = mfma(u4frag(W[9 + s]), bf, d2);
    }
    // final layer on VALU: sin#3 (rev) + f32 dot over this lane's feats
    float a0 = 0.0f, a1 = 0.0f;
#pragma unroll
    for (int r = 0; r < 16; r += 2) {
        a0 = fmaf(w4a[r],     sin_rev(d1[r]),     a0);
        a1 = fmaf(w4a[r + 1], sin_rev(d1[r + 1]), a1);
    }
#pragma unroll
    for (int r = 0; r < 4; r += 2) {
        a0 = fmaf(w4b[r],     sin_rev(d2[r]),     a0);
        a1 = fmaf(w4b[r + 1], sin_rev(d2[r + 1]), a1);
    }
    const float part = a0 + a1;
    // pair-reduce: lane l (<32) adds partner l+32's partial
    const u32x2 t = plsw(__float_as_uint(part), __float_as_uint(part));
    const float tot = part + __uint_as_float(t.y) + b4;
    return softplus(tot);   // valid at g0 lanes
}

// ---- main kernel ------------------------------------------------------------

__global__ __launch_bounds__(256) void mlp_mfma_kernel(
    const float* __restrict__ x,
    const float* __restrict__ params,     // original (32,2809)
    float* __restrict__ out)
{
    __shared__ uint4 lds_fw[14 * 64];

    const int lane = threadIdx.x & 63;
    const int wave = threadIdx.x >> 6;
    const int b    = blockIdx.y;
    const int g    = lane >> 5;

    const float* pp = params + (size_t)b * NPAR;

    // ---- phase 0: cooperative frag build into LDS (once per block) ----
#pragma unroll
    for (int k = 0; k < 4; ++k) {
        const int sid = threadIdx.x + 256 * k;   // 0..1023; 896 real slots
        if (sid < 896)
            lds_fw[sid] = build_frag_slot(pp, sid >> 6, sid & 63);
    }
    __syncthreads();

    uint4 W[12];
#pragma unroll
    for (int f = 0; f < 12; ++f)
        W[f] = lds_fw[f * 64 + lane];
    const bf16x8 w1a = u4frag(lds_fw[12 * 64 + lane]);
    const bf16x8 w1b = u4frag(lds_fw[13 * 64 + lane]);

    // ---- per-lane W4 in f32 (UNFOLDED), mapping (r&3)+8*(r>>2)+4g ----
    float w4a[16];
#pragma unroll
    for (int r = 0; r < 16; ++r)
        w4a[r] = pp[2772 + ((r & 3) + 8 * (r >> 2) + 4 * g)];
    float w4b[4];
#pragma unroll
    for (int r = 0; r < 4; ++r)
        w4b[r] = (g == 0) ? pp[2772 + 32 + r] : 0.0f;
    const float b4 = pp[2808];

    const u32 biasw = pk2(1.0f, 0.0f);

    f32x16 z;
#pragma unroll
    for (int i = 0; i < 16; ++i) z[i] = 0.0f;

#pragma unroll 1
    for (int it = 0; it < ITERS; ++it) {
        const int n = blockIdx.x * (64 * ITERS * 4) + wave * (64 * ITERS)
                    + it * 64 + lane;
        const float2 xv = reinterpret_cast<const float2*>(x)[n];

        // layer-1 B frags: own point (tile A) / partner's point (tile B).
        // g1 lanes' words sit at k-slots where W1 frag is exactly 0 -> no mask.
        const u32 pxy  = pk2(xv.x, xv.y);
        const u32 pxyB = plsw(pxy, pxy).y;

        const float spA = tile_forward(W, w1a, w1b, mkfrag(pxy,  biasw, 0, 0),
                                       w4a, w4b, b4, biasw, z);
        const float spB = tile_forward(W, w1a, w1b, mkfrag(pxyB, biasw, 0, 0),
                                       w4a, w4b, b4, biasw, z);

        // merged store (tile A -> lanes 0..31, tile B -> lanes 32..63)
        const u32x2 r = plsw(__float_as_uint(spA), __float_as_uint(spB));
        out[(size_t)b * NPTS + n] = __uint_as_float(r.x);
    }
}

extern "C" void kernel_launch(void* const* d_in, const int* in_sizes, int n_in,
                              void* d_out, int out_size, void* d_ws, size_t ws_size,
                              hipStream_t stream)
{
    const float* x = (const float*)d_in[0];
    const float* params = (const float*)d_in[1];
    float* out = (float*)d_out;

    mlp_mfma_kernel<<<dim3(NPTS / (64 * ITERS * 4), NBATCH), dim3(256), 0, stream>>>(
        x, params, out);
}